// Round 10
// baseline (306.871 us; speedup 1.0000x reference)
//
#include <hip/hip_runtime.h>
#include <hip/hip_bf16.h>
#include <stdint.h>

#define DEVI __device__ __forceinline__

typedef float f32x4 __attribute__((ext_vector_type(4)));
typedef float f32x16 __attribute__((ext_vector_type(16)));
typedef short bf16x8 __attribute__((ext_vector_type(8)));

typedef __attribute__((address_space(3))) unsigned int as3_u32;
typedef __attribute__((address_space(1))) unsigned int as1_u32;

DEVI void gload16(const void* g, void* l) {
  __builtin_amdgcn_global_load_lds((const as1_u32*)g, (as3_u32*)l, 16, 0, 0);
}

DEVI unsigned short bf16r(float f) {
  union { float f; unsigned int u; } v; v.f = f;
  unsigned int u = v.u;
  return (unsigned short)((u + 0x7FFFu + ((u >> 16) & 1u)) >> 16);
}

DEVI float bf2f(unsigned short u) {
  unsigned int x = ((unsigned int)u) << 16;
  union { unsigned int u; float f; } v; v.u = x;
  return v.f;
}

DEVI unsigned int pkbf16(float a, float b) {
  __hip_bfloat162 h = __float22bfloat162_rn(make_float2(a, b));
  return *(unsigned int*)&h;
}

// ---------------- weight prep: fp32 [K][N] -> bf16 [N][K], pack qkv biases ----
struct PrepArgs {
  const float* w[10];
  const float* b1[3];
  const float* b2[3];
};

__global__ __launch_bounds__(256) void prep_kernel(PrepArgs pa, unsigned short* wt,
                                                   float* qb1, float* qb2) {
  __shared__ float lt[64][65];
  const int slot = blockIdx.z;
  const int n0 = blockIdx.x * 64, k0 = blockIdx.y * 64;
  const float* W = pa.w[slot];
  for (int it = 0; it < 16; it++) {
    int idx = it * 256 + threadIdx.x;
    int kr = idx >> 6, nc = idx & 63;
    lt[kr][nc] = W[(long)(k0 + kr) * 512 + n0 + nc];
  }
  __syncthreads();
  unsigned short* dst = wt + (long)slot * 512 * 512;
  for (int it = 0; it < 16; it++) {
    int idx = it * 256 + threadIdx.x;
    int nr = idx >> 6, kc = idx & 63;
    dst[(long)(n0 + nr) * 512 + k0 + kc] = bf16r(lt[kc][nr]);
  }
  if (blockIdx.x == 0 && blockIdx.y == 0) {
    if (slot < 3) {
      for (int i = threadIdx.x; i < 512; i += 256) qb1[slot * 512 + i] = pa.b1[slot][i];
    } else if (slot >= 6 && slot < 9) {
      for (int i = threadIdx.x; i < 512; i += 256) qb2[(slot - 6) * 512 + i] = pa.b2[slot - 6][i];
    }
  }
}

// ---------------- l2 normalize rows of x, fp32 -> bf16 -----------------------
__global__ __launch_bounds__(256) void l2norm_kernel(const float* __restrict__ x,
                                                     unsigned short* __restrict__ xn) {
  const long row = blockIdx.x;
  const float* xr = x + row * 512;
  float v0 = xr[threadIdx.x], v1 = xr[threadIdx.x + 256];
  float ss = v0 * v0 + v1 * v1;
  #pragma unroll
  for (int off = 32; off > 0; off >>= 1) ss += __shfl_down(ss, off, 64);
  __shared__ float red[4];
  __shared__ float sc[1];
  int w = threadIdx.x >> 6, ln = threadIdx.x & 63;
  if (ln == 0) red[w] = ss;
  __syncthreads();
  if (threadIdx.x == 0) {
    float S = red[0] + red[1] + red[2] + red[3];
    sc[0] = 1.0f / fmaxf(sqrtf(S), 1e-12f);
  }
  __syncthreads();
  float s = sc[0];
  xn[row * 512 + threadIdx.x] = bf16r(v0 * s);
  xn[row * 512 + threadIdx.x + 256] = bf16r(v1 * s);
}

// ---------------- GEMM 128x128: C = A x Bt^T + bias --------------------------
// EPI: 0 = f32 out, 1 = bf16 out, 2 = bf16 out + relu,
//      3 = bf16 out; cols >=1024 are V -> written transposed into vtout
template <int EPI>
__global__ __launch_bounds__(256) void gemm_bt(const unsigned short* __restrict__ A,
                                               const unsigned short* __restrict__ Bt,
                                               const float* __restrict__ bias,
                                               void* __restrict__ Cv, int K, int N,
                                               unsigned short* __restrict__ vtout) {
  __shared__ unsigned short ldsA[128 * 64];
  __shared__ unsigned short ldsB[128 * 64];
  const int tid = threadIdx.x, w = tid >> 6, ln = tid & 63;
  const int bm = blockIdx.x, bn = blockIdx.y;
  const int wm = (w >> 1) * 64, wn = (w & 1) * 64;
  const f32x4 zf = {0.f, 0.f, 0.f, 0.f};
  f32x4 acc[4][4];
  #pragma unroll
  for (int i = 0; i < 4; i++)
    #pragma unroll
    for (int j = 0; j < 4; j++) acc[i][j] = zf;
  const int r8 = ln >> 3, s8 = ln & 7;
  for (int kt = 0; kt < K; kt += 64) {
    #pragma unroll
    for (int i = 0; i < 4; i++) {
      int row = w * 32 + i * 8 + r8;
      gload16(A + (long)(bm * 128 + row) * K + kt + s8 * 8, &ldsA[(w * 32 + i * 8) * 64]);
      gload16(Bt + (long)(bn * 128 + row) * K + kt + s8 * 8, &ldsB[(w * 32 + i * 8) * 64]);
    }
    __syncthreads();
    #pragma unroll
    for (int kk = 0; kk < 2; kk++) {
      bf16x8 af[4], bfr[4];
      #pragma unroll
      for (int mf = 0; mf < 4; mf++) {
        int row = wm + mf * 16 + (ln & 15);
        af[mf] = *(const bf16x8*)&ldsA[row * 64 + kk * 32 + (ln >> 4) * 8];
      }
      #pragma unroll
      for (int nf = 0; nf < 4; nf++) {
        int row = wn + nf * 16 + (ln & 15);
        bfr[nf] = *(const bf16x8*)&ldsB[row * 64 + kk * 32 + (ln >> 4) * 8];
      }
      #pragma unroll
      for (int mf = 0; mf < 4; mf++)
        #pragma unroll
        for (int nf = 0; nf < 4; nf++)
          acc[mf][nf] = __builtin_amdgcn_mfma_f32_16x16x32_bf16(af[mf], bfr[nf], acc[mf][nf], 0, 0, 0);
    }
    __syncthreads();
  }
  const int g = ln >> 4, c = ln & 15;
  #pragma unroll
  for (int mf = 0; mf < 4; mf++) {
    #pragma unroll
    for (int nf = 0; nf < 4; nf++) {
      int col = bn * 128 + wn + nf * 16 + c;
      float bv = bias[col];
      if (EPI == 3 && col >= 1024) {
        long row0 = bm * 128 + wm + mf * 16 + g * 4;
        int b = (int)(row0 >> 11), s = (int)(row0 & 2047);
        int vc = col - 1024, h = vc >> 6, hd = vc & 63;
        ushort4 o;
        o.x = bf16r(acc[mf][nf][0] + bv);
        o.y = bf16r(acc[mf][nf][1] + bv);
        o.z = bf16r(acc[mf][nf][2] + bv);
        o.w = bf16r(acc[mf][nf][3] + bv);
        *(ushort4*)(vtout + ((long)((b * 8 + h) * 64 + hd)) * 2048 + s) = o;
      } else {
        #pragma unroll
        for (int j = 0; j < 4; j++) {
          long row = bm * 128 + wm + mf * 16 + g * 4 + j;
          float v = acc[mf][nf][j] + bv;
          if (EPI == 2) v = v > 0.f ? v : 0.f;
          if (EPI == 0)
            ((float*)Cv)[row * N + col] = v;
          else
            ((unsigned short*)Cv)[row * N + col] = bf16r(v);
        }
      }
    }
  }
}

// ---------------- GEMM 128x64 tile (for N=512 chains: 512 blocks, 2/CU) ------
template <int EPI>
__global__ __launch_bounds__(256) void gemm_bt64(const unsigned short* __restrict__ A,
                                                 const unsigned short* __restrict__ Bt,
                                                 const float* __restrict__ bias,
                                                 void* __restrict__ Cv, int K, int N) {
  __shared__ unsigned short ldsA[128 * 64];
  __shared__ unsigned short ldsB[64 * 64];
  const int tid = threadIdx.x, w = tid >> 6, ln = tid & 63;
  const int bm = blockIdx.x, bn = blockIdx.y;
  const int wm = (w >> 1) * 64, wn = (w & 1) * 32;
  const f32x4 zf = {0.f, 0.f, 0.f, 0.f};
  f32x4 acc[4][2];
  #pragma unroll
  for (int i = 0; i < 4; i++)
    #pragma unroll
    for (int j = 0; j < 2; j++) acc[i][j] = zf;
  const int r8 = ln >> 3, s8 = ln & 7;
  for (int kt = 0; kt < K; kt += 64) {
    #pragma unroll
    for (int i = 0; i < 6; i++) {
      int jj = w * 6 + i;
      if (jj < 16) {
        gload16(A + (long)(bm * 128 + jj * 8 + r8) * K + kt + s8 * 8, &ldsA[jj * 512]);
      } else {
        int jb = jj - 16;
        gload16(Bt + (long)(bn * 64 + jb * 8 + r8) * K + kt + s8 * 8, &ldsB[jb * 512]);
      }
    }
    __syncthreads();
    #pragma unroll
    for (int kk = 0; kk < 2; kk++) {
      bf16x8 af[4], bfr[2];
      #pragma unroll
      for (int mf = 0; mf < 4; mf++)
        af[mf] = *(const bf16x8*)&ldsA[(wm + mf * 16 + (ln & 15)) * 64 + kk * 32 + (ln >> 4) * 8];
      #pragma unroll
      for (int nf = 0; nf < 2; nf++)
        bfr[nf] = *(const bf16x8*)&ldsB[(wn + nf * 16 + (ln & 15)) * 64 + kk * 32 + (ln >> 4) * 8];
      #pragma unroll
      for (int mf = 0; mf < 4; mf++)
        #pragma unroll
        for (int nf = 0; nf < 2; nf++)
          acc[mf][nf] = __builtin_amdgcn_mfma_f32_16x16x32_bf16(af[mf], bfr[nf], acc[mf][nf], 0, 0, 0);
    }
    __syncthreads();
  }
  const int g = ln >> 4, c = ln & 15;
  #pragma unroll
  for (int mf = 0; mf < 4; mf++) {
    #pragma unroll
    for (int nf = 0; nf < 2; nf++) {
      int col = bn * 64 + wn + nf * 16 + c;
      float bv = bias[col];
      #pragma unroll
      for (int j = 0; j < 4; j++) {
        long row = bm * 128 + wm + mf * 16 + g * 4 + j;
        float v = acc[mf][nf][j] + bv;
        if (EPI == 2) v = v > 0.f ? v : 0.f;
        if (EPI == 0)
          ((float*)Cv)[row * N + col] = v;
        else
          ((unsigned short*)Cv)[row * N + col] = bf16r(v);
      }
    }
  }
}

// ---------------- fused attention, split-K=2, 32x32 MFMA, in-register P ------
// QK^T: mfma32(K,Q) -> S^T: lane(hi=l>>5, lo=l&31) holds S^T[key=(r&3)+8*(r>>2)+4*hi][query=lo].
// P^T for PV assembled in-register via cvt_pk + __shfl_xor(.,32) half swaps.
// PV: mfma32(V^T, P^T) -> O^T[hd][query], hd rows per same reg pattern.
// K LDS: [32 rows][8 x 16B slots], slot ^(row&7).  V LDS: [64 rows][4 x 16B], slot ^((row>>1)&3).
__global__ __launch_bounds__(256, 4) void attn_split_kernel(
    const unsigned short* __restrict__ qkv,
    const unsigned short* __restrict__ vt,
    const float* __restrict__ mask,
    unsigned short* __restrict__ opart,  // [2][32][2048][64] bf16 (unnormalized)
    float* __restrict__ lpart) {         // [2][32][2048] f32
  const int tid = threadIdx.x, w = tid >> 6, ln = tid & 63;
  const int lo = ln & 31, hi = ln >> 5;
  // XCD-aware bijective swizzle (1024 = 8 x 128)
  const int bid = blockIdx.x + 16 * blockIdx.y + 512 * blockIdx.z;
  const int swz = (bid & 7) * 128 + (bid >> 3);
  const int qb = swz & 15, bh = (swz >> 4) & 31, sp = swz >> 9;
  const int b = bh >> 3, h = bh & 7;
  const int q0 = qb * 128 + w * 32;
  const unsigned short* qp = qkv + (long)(b * 2048) * 1536 + h * 64;
  const unsigned short* kp = qp + 512;
  const unsigned short* vtp = vt + (long)bh * 64 * 2048;
  const float* mp = mask + b * 2048;

  __shared__ unsigned short kbuf[2][32 * 64];  // 4KB each
  __shared__ unsigned short vbuf[2][64 * 32];  // 4KB each

  const int jj0 = w * 2;
  auto stage = [&](int buf, int kt) {
    #pragma unroll
    for (int u = 0; u < 2; u++) {
      int jj = jj0 + u;
      if (jj < 4) {
        int r = jj * 8 + (ln >> 3);
        int s = ln & 7;
        gload16(kp + (long)(kt + r) * 1536 + ((s ^ (r & 7)) * 8),
                &kbuf[buf][jj * 512]);
      } else {
        int j = jj - 4;
        int r = j * 16 + (ln >> 2);
        int s = ln & 3;
        gload16(vtp + (long)r * 2048 + kt + ((s ^ ((r >> 1) & 3)) * 8),
                &vbuf[buf][j * 512]);
      }
    }
  };

  // Q fragments (B-operand, hoisted): Q[q0+lo][kdim t*16 + hi*8 .. +7]
  bf16x8 qf[4];
  #pragma unroll
  for (int t = 0; t < 4; t++)
    qf[t] = *(const bf16x8*)(qp + (long)(q0 + lo) * 1536 + t * 16 + hi * 8);

  f32x16 oacc[2];
  #pragma unroll
  for (int t = 0; t < 2; t++)
    #pragma unroll
    for (int r = 0; r < 16; r++) oacc[t][r] = 0.f;
  float lsum = 0.f;
  const f32x16 zf16 = oacc[0];

  const int kt0 = sp * 1024;
  stage(0, kt0);
  __syncthreads();

  for (int it = 0; it < 32; it++) {
    const int kt = kt0 + it * 32;
    const int cur = it & 1;
    if (it + 1 < 32) stage(cur ^ 1, kt + 32);
    float mval = mp[kt + lo];
    // QK^T: 4 MFMA over kdim
    f32x16 sacc = zf16;
    #pragma unroll
    for (int t = 0; t < 4; t++) {
      bf16x8 kf = *(const bf16x8*)&kbuf[cur][lo * 64 + (((t * 2 + hi) ^ (lo & 7)) * 8)];
      sacc = __builtin_amdgcn_mfma_f32_32x32x16_bf16(kf, qf[t], sacc, 0, 0, 0);
    }
    // softmax numerators (exp2, folded 0.125*log2e); mask fast path
    const float SC = 0.18033688011112042f;
    float e[16];
    if (__any(mval != 0.f)) {
      #pragma unroll
      for (int r = 0; r < 16; r++) {
        float mk = __shfl(mval, (r & 3) + 8 * (r >> 2) + 4 * hi, 64);
        e[r] = __builtin_amdgcn_exp2f(sacc[r] * SC - 1.4426950408889634e30f * mk);
      }
    } else {
      #pragma unroll
      for (int r = 0; r < 16; r++)
        e[r] = __builtin_amdgcn_exp2f(sacc[r] * SC);
    }
    #pragma unroll
    for (int r = 0; r < 16; r++) lsum += e[r];
    // pack to bf16 pairs; assemble P^T fragments via half-swaps
    unsigned int cv[8];
    #pragma unroll
    for (int i = 0; i < 8; i++) cv[i] = pkbf16(e[2 * i], e[2 * i + 1]);
    #pragma unroll
    for (int stt = 0; stt < 2; stt++) {
      unsigned int c0 = cv[stt * 4 + 0], c1 = cv[stt * 4 + 1];
      unsigned int c2 = cv[stt * 4 + 2], c3 = cv[stt * 4 + 3];
      unsigned int s0 = __shfl_xor(c0, 32, 64), s1 = __shfl_xor(c1, 32, 64);
      unsigned int s2 = __shfl_xor(c2, 32, 64), s3 = __shfl_xor(c3, 32, 64);
      unsigned int pf[4];
      pf[0] = hi ? s2 : c0;
      pf[1] = hi ? s3 : c1;
      pf[2] = hi ? c2 : s0;
      pf[3] = hi ? c3 : s1;
      bf16x8 pfr = *(const bf16x8*)pf;
      #pragma unroll
      for (int tau = 0; tau < 2; tau++) {
        int vr = tau * 32 + lo;
        bf16x8 vf = *(const bf16x8*)&vbuf[cur][vr * 32 + ((((stt * 2 + hi) ^ ((vr >> 1) & 3))) * 8)];
        oacc[tau] = __builtin_amdgcn_mfma_f32_32x32x16_bf16(vf, pfr, oacc[tau], 0, 0, 0);
      }
    }
    __syncthreads();
  }
  lsum += __shfl_xor(lsum, 32, 64);
  unsigned short* ob = opart + (long)(sp * 32 + bh) * 2048 * 64;
  const long row = q0 + lo;
  #pragma unroll
  for (int tau = 0; tau < 2; tau++) {
    #pragma unroll
    for (int j = 0; j < 4; j++) {
      ushort4 o;
      o.x = bf16r(oacc[tau][4 * j + 0]);
      o.y = bf16r(oacc[tau][4 * j + 1]);
      o.z = bf16r(oacc[tau][4 * j + 2]);
      o.w = bf16r(oacc[tau][4 * j + 3]);
      *(ushort4*)(ob + row * 64 + tau * 32 + j * 8 + hi * 4) = o;
    }
  }
  if (hi == 0)
    lpart[(long)(sp * 32 + bh) * 2048 + row] = lsum;
}

// ---------------- combine split-K partials -> ao (bf16) ----------------------
__global__ __launch_bounds__(256) void attn_combine(const unsigned short* __restrict__ opart,
                                                    const float* __restrict__ lpart,
                                                    unsigned short* __restrict__ ao) {
  const long row = blockIdx.x;           // b*2048 + q
  const int b = (int)(row >> 11), q = (int)(row & 2047);
  #pragma unroll
  for (int half = 0; half < 2; half++) {
    int col = threadIdx.x + half * 256;
    int h = col >> 6, hd = col & 63;
    int bh = b * 8 + h;
    float l = lpart[(long)bh * 2048 + q] + lpart[(long)(32 + bh) * 2048 + q];
    long i0 = ((long)bh * 2048 + q) * 64 + hd;
    long i1 = ((long)(32 + bh) * 2048 + q) * 64 + hd;
    float v = (bf2f(opart[i0]) + bf2f(opart[i1])) / l;
    ao[row * 512 + col] = bf16r(v);
  }
}

// ---------------- layernorm rows, fp32 in; OUTF 0 = bf16 out, 1 = f32 out ----
template <int OUTF>
__global__ __launch_bounds__(256) void ln_kernel(const float* __restrict__ in,
                                                 const float* __restrict__ gam,
                                                 const float* __restrict__ bet,
                                                 void* __restrict__ out) {
  const long row = blockIdx.x;
  const float* x = in + row * 512;
  float v0 = x[threadIdx.x], v1 = x[threadIdx.x + 256];
  float s = v0 + v1, ss = v0 * v0 + v1 * v1;
  #pragma unroll
  for (int off = 32; off > 0; off >>= 1) {
    s += __shfl_down(s, off, 64);
    ss += __shfl_down(ss, off, 64);
  }
  __shared__ float red[8];
  __shared__ float mv[2];
  int w = threadIdx.x >> 6, ln = threadIdx.x & 63;
  if (ln == 0) { red[w] = s; red[w + 4] = ss; }
  __syncthreads();
  if (threadIdx.x == 0) {
    float S = red[0] + red[1] + red[2] + red[3];
    float SS = red[4] + red[5] + red[6] + red[7];
    float mu = S * (1.f / 512.f);
    float var = SS * (1.f / 512.f) - mu * mu;
    mv[0] = mu;
    mv[1] = rsqrtf(var + 1e-5f);
  }
  __syncthreads();
  float mu = mv[0], rs = mv[1];
  float o0 = (v0 - mu) * rs * gam[threadIdx.x] + bet[threadIdx.x];
  float o1 = (v1 - mu) * rs * gam[threadIdx.x + 256] + bet[threadIdx.x + 256];
  if (OUTF == 0) {
    ((unsigned short*)out)[row * 512 + threadIdx.x] = bf16r(o0);
    ((unsigned short*)out)[row * 512 + threadIdx.x + 256] = bf16r(o1);
  } else {
    ((float*)out)[row * 512 + threadIdx.x] = o0;
    ((float*)out)[row * 512 + threadIdx.x + 256] = o1;
  }
}

// ---------------- pool: alpha = leaky_relu(h @ pw + pb) + mask*-1e16 ---------
__global__ __launch_bounds__(256) void alpha_kernel(const float* __restrict__ h,
                                                    const float* __restrict__ pw,
                                                    const float* __restrict__ pbias,
                                                    const float* __restrict__ mask,
                                                    float* __restrict__ alpha) {
  int w = threadIdx.x >> 6, ln = threadIdx.x & 63;
  long row = (long)blockIdx.x * 4 + w;
  float p[8];
  #pragma unroll
  for (int k = 0; k < 8; k++) p[k] = 0.f;
  #pragma unroll
  for (int it = 0; it < 8; it++) {
    int d = it * 64 + ln;
    float xv = h[row * 512 + d];
    const float* wr = pw + d * 8;
    #pragma unroll
    for (int k = 0; k < 8; k++) p[k] += xv * wr[k];
  }
  #pragma unroll
  for (int off = 32; off > 0; off >>= 1)
    #pragma unroll
    for (int k = 0; k < 8; k++) p[k] += __shfl_down(p[k], off, 64);
  if (ln == 0) {
    float mterm = mask[row] * (-1e16f);
    #pragma unroll
    for (int k = 0; k < 8; k++) {
      float a = p[k] + pbias[k];
      a = a < 0.f ? 0.01f * a : a;
      alpha[row * 8 + k] = a + mterm;
    }
  }
}

__global__ __launch_bounds__(256) void stats_kernel(const float* __restrict__ alpha,
                                                    float* __restrict__ stats) {
  int b = blockIdx.x >> 3, ph = blockIdx.x & 7;
  const float* a = alpha + (long)b * 2048 * 8 + ph;
  __shared__ float rr[4];
  __shared__ float mm[1];
  int w = threadIdx.x >> 6, ln = threadIdx.x & 63;
  float m = -1e38f;
  for (int s = threadIdx.x; s < 2048; s += 256) m = fmaxf(m, a[(long)s * 8]);
  #pragma unroll
  for (int off = 32; off > 0; off >>= 1) m = fmaxf(m, __shfl_down(m, off, 64));
  if (ln == 0) rr[w] = m;
  __syncthreads();
  if (threadIdx.x == 0) mm[0] = fmaxf(fmaxf(rr[0], rr[1]), fmaxf(rr[2], rr[3]));
  __syncthreads();
  float M = mm[0];
  float sum = 0.f;
  for (int s = threadIdx.x; s < 2048; s += 256) sum += __expf(a[(long)s * 8] - M);
  #pragma unroll
  for (int off = 32; off > 0; off >>= 1) sum += __shfl_down(sum, off, 64);
  __syncthreads();
  if (ln == 0) rr[w] = sum;
  __syncthreads();
  if (threadIdx.x == 0) {
    stats[blockIdx.x * 2] = M;
    stats[blockIdx.x * 2 + 1] = rr[0] + rr[1] + rr[2] + rr[3];
  }
}

// partial[sc + b*8][d] = sum over its 256-seq chunk of w(s) * h[s][d]
__global__ __launch_bounds__(256) void pool_kernel(const float* __restrict__ h,
                                                   const float* __restrict__ alpha,
                                                   const float* __restrict__ stats,
                                                   float* __restrict__ partial) {
  int b = blockIdx.x >> 3, sc = blockIdx.x & 7;
  int s0 = sc * 256;
  __shared__ float wb[256];
  {
    long s = s0 + threadIdx.x;
    const float* a = alpha + ((long)b * 2048 + s) * 8;
    float wsum = 0.f;
    #pragma unroll
    for (int ph = 0; ph < 8; ph++) {
      float M = stats[(b * 8 + ph) * 2], Sm = stats[(b * 8 + ph) * 2 + 1];
      wsum += __expf(a[ph] - M) / Sm;
    }
    wb[threadIdx.x] = wsum;
  }
  __syncthreads();
  float a0 = 0.f, a1 = 0.f;
  const float* hb = h + ((long)b * 2048 + s0) * 512;
  for (int i = 0; i < 256; i++) {
    float wv = wb[i];
    a0 += wv * hb[(long)i * 512 + threadIdx.x];
    a1 += wv * hb[(long)i * 512 + threadIdx.x + 256];
  }
  partial[(long)blockIdx.x * 512 + threadIdx.x] = a0;
  partial[(long)blockIdx.x * 512 + threadIdx.x + 256] = a1;
}

__global__ __launch_bounds__(256) void pool_final(const float* __restrict__ partial,
                                                  float* __restrict__ out) {
  int b = blockIdx.x;
  float a0 = 0.f, a1 = 0.f;
  #pragma unroll
  for (int sc = 0; sc < 8; sc++) {
    a0 += partial[(long)(b * 8 + sc) * 512 + threadIdx.x];
    a1 += partial[(long)(b * 8 + sc) * 512 + threadIdx.x + 256];
  }
  out[b * 512 + threadIdx.x] = a0;
  out[b * 512 + threadIdx.x + 256] = a1;
}

// -----------------------------------------------------------------------------
extern "C" void kernel_launch(void* const* d_in, const int* in_sizes, int n_in,
                              void* d_out, int out_size, void* d_ws, size_t ws_size,
                              hipStream_t stream) {
  (void)in_sizes; (void)n_in; (void)out_size;
  if (ws_size < 92274688UL) return;  // need ~88MB scratch

  const float* x    = (const float*)d_in[0];
  const float* mask = (const float*)d_in[1];
  const float* q1w = (const float*)d_in[2];  const float* q1b = (const float*)d_in[3];
  const float* k1w = (const float*)d_in[4];  const float* k1b = (const float*)d_in[5];
  const float* v1w = (const float*)d_in[6];  const float* v1b = (const float*)d_in[7];
  const float* o1w = (const float*)d_in[8];  const float* o1b = (const float*)d_in[9];
  const float* q2w = (const float*)d_in[10]; const float* q2b = (const float*)d_in[11];
  const float* k2w = (const float*)d_in[12]; const float* k2b = (const float*)d_in[13];
  const float* v2w = (const float*)d_in[14]; const float* v2b = (const float*)d_in[15];
  const float* o2w = (const float*)d_in[16]; const float* o2b = (const float*)d_in[17];
  const float* ln1g = (const float*)d_in[18]; const float* ln1b = (const float*)d_in[19];
  const float* fw1 = (const float*)d_in[20]; const float* fb1 = (const float*)d_in[21];
  const float* fw2 = (const float*)d_in[22]; const float* fb2 = (const float*)d_in[23];
  const float* ln2g = (const float*)d_in[24]; const float* ln2b = (const float*)d_in[25];
  const float* poolw = (const float*)d_in[26]; const float* poolb = (const float*)d_in[27];

  char* ws = (char*)d_ws;
  unsigned short* Wt  = (unsigned short*)(ws + 0);          // 10 x 512x512 bf16 (5MB)
  float* qb1          = (float*)(ws + 5242880);
  float* qb2          = (float*)(ws + 5249024);
  float* stats        = (float*)(ws + 5255168);
  float* alpha        = (float*)(ws + 5255424);             // 256KB
  float* partial      = (float*)(ws + 5517568);             // 64KB
  unsigned short* qkv = (unsigned short*)(ws + 8388608);    // [8192][1536] bf16 (24MB)
  unsigned short* vt  = (unsigned short*)(ws + 33554432);   // [32][64][2048] bf16 (8MB)
  unsigned short* ao  = (unsigned short*)(ws + 41943040);   // [8192][512] bf16 (8MB)
  float* t            = (float*)(ws + 50331648);            // [8192][512] f32 (16MB)
  unsigned short* xn  = (unsigned short*)(ws + 67108864);   // [8192][512] bf16 (8MB)
  unsigned short* h1  = (unsigned short*)(ws + 75497472);   // (8MB)
  unsigned short* f   = (unsigned short*)(ws + 83886080);   // (8MB)
  unsigned short* h2  = xn;                                 // xn dead by then
  // attention split-K partials: live ONLY during attn+combine; [t] is dead then.
  unsigned short* opart = (unsigned short*)(ws + 50331648); // 16.8MB [2][32][2048][64] bf16
  float* lpart          = (float*)(ws + 83886080);          // 512KB [2][32][2048] (dead f)

  PrepArgs pa;
  pa.w[0] = q1w; pa.w[1] = k1w; pa.w[2] = v1w; pa.w[3] = o1w; pa.w[4] = fw1;
  pa.w[5] = fw2; pa.w[6] = q2w; pa.w[7] = k2w; pa.w[8] = v2w; pa.w[9] = o2w;
  pa.b1[0] = q1b; pa.b1[1] = k1b; pa.b1[2] = v1b;
  pa.b2[0] = q2b; pa.b2[1] = k2b; pa.b2[2] = v2b;

  prep_kernel<<<dim3(8, 8, 10), 256, 0, stream>>>(pa, Wt, qb1, qb2);
  l2norm_kernel<<<8192, 256, 0, stream>>>(x, xn);

  // layer 1 (QKV GEMM writes V directly transposed into vt)
  gemm_bt<3><<<dim3(64, 12), 256, 0, stream>>>(xn, Wt, qb1, qkv, 512, 1536, vt);
  attn_split_kernel<<<dim3(16, 32, 2), 256, 0, stream>>>(qkv, vt, mask, opart, lpart);
  attn_combine<<<8192, 256, 0, stream>>>(opart, lpart, ao);
  gemm_bt64<0><<<dim3(64, 8), 256, 0, stream>>>(ao, Wt + 3L * 512 * 512, o1b, t, 512, 512);
  ln_kernel<0><<<8192, 256, 0, stream>>>(t, ln1g, ln1b, h1);
  gemm_bt64<2><<<dim3(64, 8), 256, 0, stream>>>(h1, Wt + 4L * 512 * 512, fb1, f, 512, 512);
  gemm_bt64<1><<<dim3(64, 8), 256, 0, stream>>>(f, Wt + 5L * 512 * 512, fb2, h2, 512, 512);

  // layer 2
  gemm_bt<3><<<dim3(64, 12), 256, 0, stream>>>(h2, Wt + 6L * 512 * 512, qb2, qkv, 512, 1536, vt);
  attn_split_kernel<<<dim3(16, 32, 2), 256, 0, stream>>>(qkv, vt, mask, opart, lpart);
  attn_combine<<<8192, 256, 0, stream>>>(opart, lpart, ao);
  gemm_bt64<0><<<dim3(64, 8), 256, 0, stream>>>(ao, Wt + 9L * 512 * 512, o2b, t, 512, 512);
  ln_kernel<1><<<8192, 256, 0, stream>>>(t, ln2g, ln2b, t);  // in-place f32

  // pooling
  alpha_kernel<<<2048, 256, 0, stream>>>(t, poolw, poolb, mask, alpha);
  stats_kernel<<<32, 256, 0, stream>>>(alpha, stats);
  pool_kernel<<<32, 256, 0, stream>>>(t, alpha, stats, partial);
  pool_final<<<4, 256, 0, stream>>>(partial, (float*)d_out);
}

// Round 11
// 303.499 us; speedup vs baseline: 1.0111x; 1.0111x over previous
//
#include <hip/hip_runtime.h>
#include <hip/hip_bf16.h>
#include <stdint.h>

#define DEVI __device__ __forceinline__

typedef float f32x4 __attribute__((ext_vector_type(4)));
typedef float f32x16 __attribute__((ext_vector_type(16)));
typedef short bf16x8 __attribute__((ext_vector_type(8)));

typedef __attribute__((address_space(3))) unsigned int as3_u32;
typedef __attribute__((address_space(1))) unsigned int as1_u32;

DEVI void gload16(const void* g, void* l) {
  __builtin_amdgcn_global_load_lds((const as1_u32*)g, (as3_u32*)l, 16, 0, 0);
}

DEVI unsigned short bf16r(float f) {
  union { float f; unsigned int u; } v; v.f = f;
  unsigned int u = v.u;
  return (unsigned short)((u + 0x7FFFu + ((u >> 16) & 1u)) >> 16);
}

DEVI float bf2f(unsigned short u) {
  unsigned int x = ((unsigned int)u) << 16;
  union { unsigned int u; float f; } v; v.u = x;
  return v.f;
}

DEVI unsigned int pkbf16(float a, float b) {
  __hip_bfloat162 h = __float22bfloat162_rn(make_float2(a, b));
  return *(unsigned int*)&h;
}

// ---------------- weight prep: fp32 [K][N] -> bf16 [N][K], pack qkv biases ----
struct PrepArgs {
  const float* w[10];
  const float* b1[3];
  const float* b2[3];
};

__global__ __launch_bounds__(256) void prep_kernel(PrepArgs pa, unsigned short* wt,
                                                   float* qb1, float* qb2) {
  __shared__ float lt[64][65];
  const int slot = blockIdx.z;
  const int n0 = blockIdx.x * 64, k0 = blockIdx.y * 64;
  const float* W = pa.w[slot];
  for (int it = 0; it < 16; it++) {
    int idx = it * 256 + threadIdx.x;
    int kr = idx >> 6, nc = idx & 63;
    lt[kr][nc] = W[(long)(k0 + kr) * 512 + n0 + nc];
  }
  __syncthreads();
  unsigned short* dst = wt + (long)slot * 512 * 512;
  for (int it = 0; it < 16; it++) {
    int idx = it * 256 + threadIdx.x;
    int nr = idx >> 6, kc = idx & 63;
    dst[(long)(n0 + nr) * 512 + k0 + kc] = bf16r(lt[kc][nr]);
  }
  if (blockIdx.x == 0 && blockIdx.y == 0) {
    if (slot < 3) {
      for (int i = threadIdx.x; i < 512; i += 256) qb1[slot * 512 + i] = pa.b1[slot][i];
    } else if (slot >= 6 && slot < 9) {
      for (int i = threadIdx.x; i < 512; i += 256) qb2[(slot - 6) * 512 + i] = pa.b2[slot - 6][i];
    }
  }
}

// ---------------- l2 normalize rows of x, fp32 -> bf16 -----------------------
__global__ __launch_bounds__(256) void l2norm_kernel(const float* __restrict__ x,
                                                     unsigned short* __restrict__ xn) {
  const long row = blockIdx.x;
  const float* xr = x + row * 512;
  float v0 = xr[threadIdx.x], v1 = xr[threadIdx.x + 256];
  float ss = v0 * v0 + v1 * v1;
  #pragma unroll
  for (int off = 32; off > 0; off >>= 1) ss += __shfl_down(ss, off, 64);
  __shared__ float red[4];
  __shared__ float sc[1];
  int w = threadIdx.x >> 6, ln = threadIdx.x & 63;
  if (ln == 0) red[w] = ss;
  __syncthreads();
  if (threadIdx.x == 0) {
    float S = red[0] + red[1] + red[2] + red[3];
    sc[0] = 1.0f / fmaxf(sqrtf(S), 1e-12f);
  }
  __syncthreads();
  float s = sc[0];
  xn[row * 512 + threadIdx.x] = bf16r(v0 * s);
  xn[row * 512 + threadIdx.x + 256] = bf16r(v1 * s);
}

// ---------------- GEMM 128x128: C = A x Bt^T + bias --------------------------
// EPI: 0 = f32 out, 1 = bf16 out, 2 = bf16 out + relu,
//      3 = bf16 out; cols >=1024 are V -> written transposed into vtout
template <int EPI>
__global__ __launch_bounds__(256) void gemm_bt(const unsigned short* __restrict__ A,
                                               const unsigned short* __restrict__ Bt,
                                               const float* __restrict__ bias,
                                               void* __restrict__ Cv, int K, int N,
                                               unsigned short* __restrict__ vtout) {
  __shared__ unsigned short ldsA[128 * 64];
  __shared__ unsigned short ldsB[128 * 64];
  const int tid = threadIdx.x, w = tid >> 6, ln = tid & 63;
  const int bm = blockIdx.x, bn = blockIdx.y;
  const int wm = (w >> 1) * 64, wn = (w & 1) * 64;
  const f32x4 zf = {0.f, 0.f, 0.f, 0.f};
  f32x4 acc[4][4];
  #pragma unroll
  for (int i = 0; i < 4; i++)
    #pragma unroll
    for (int j = 0; j < 4; j++) acc[i][j] = zf;
  const int r8 = ln >> 3, s8 = ln & 7;
  for (int kt = 0; kt < K; kt += 64) {
    #pragma unroll
    for (int i = 0; i < 4; i++) {
      int row = w * 32 + i * 8 + r8;
      gload16(A + (long)(bm * 128 + row) * K + kt + s8 * 8, &ldsA[(w * 32 + i * 8) * 64]);
      gload16(Bt + (long)(bn * 128 + row) * K + kt + s8 * 8, &ldsB[(w * 32 + i * 8) * 64]);
    }
    __syncthreads();
    #pragma unroll
    for (int kk = 0; kk < 2; kk++) {
      bf16x8 af[4], bfr[4];
      #pragma unroll
      for (int mf = 0; mf < 4; mf++) {
        int row = wm + mf * 16 + (ln & 15);
        af[mf] = *(const bf16x8*)&ldsA[row * 64 + kk * 32 + (ln >> 4) * 8];
      }
      #pragma unroll
      for (int nf = 0; nf < 4; nf++) {
        int row = wn + nf * 16 + (ln & 15);
        bfr[nf] = *(const bf16x8*)&ldsB[row * 64 + kk * 32 + (ln >> 4) * 8];
      }
      #pragma unroll
      for (int mf = 0; mf < 4; mf++)
        #pragma unroll
        for (int nf = 0; nf < 4; nf++)
          acc[mf][nf] = __builtin_amdgcn_mfma_f32_16x16x32_bf16(af[mf], bfr[nf], acc[mf][nf], 0, 0, 0);
    }
    __syncthreads();
  }
  const int g = ln >> 4, c = ln & 15;
  #pragma unroll
  for (int mf = 0; mf < 4; mf++) {
    #pragma unroll
    for (int nf = 0; nf < 4; nf++) {
      int col = bn * 128 + wn + nf * 16 + c;
      float bv = bias[col];
      if (EPI == 3 && col >= 1024) {
        long row0 = bm * 128 + wm + mf * 16 + g * 4;
        int b = (int)(row0 >> 11), s = (int)(row0 & 2047);
        int vc = col - 1024, h = vc >> 6, hd = vc & 63;
        ushort4 o;
        o.x = bf16r(acc[mf][nf][0] + bv);
        o.y = bf16r(acc[mf][nf][1] + bv);
        o.z = bf16r(acc[mf][nf][2] + bv);
        o.w = bf16r(acc[mf][nf][3] + bv);
        *(ushort4*)(vtout + ((long)((b * 8 + h) * 64 + hd)) * 2048 + s) = o;
      } else {
        #pragma unroll
        for (int j = 0; j < 4; j++) {
          long row = bm * 128 + wm + mf * 16 + g * 4 + j;
          float v = acc[mf][nf][j] + bv;
          if (EPI == 2) v = v > 0.f ? v : 0.f;
          if (EPI == 0)
            ((float*)Cv)[row * N + col] = v;
          else
            ((unsigned short*)Cv)[row * N + col] = bf16r(v);
        }
      }
    }
  }
}

// ---------------- GEMM 128x64 tile (for N=512 chains: 512 blocks, 2/CU) ------
template <int EPI>
__global__ __launch_bounds__(256) void gemm_bt64(const unsigned short* __restrict__ A,
                                                 const unsigned short* __restrict__ Bt,
                                                 const float* __restrict__ bias,
                                                 void* __restrict__ Cv, int K, int N) {
  __shared__ unsigned short ldsA[128 * 64];
  __shared__ unsigned short ldsB[64 * 64];
  const int tid = threadIdx.x, w = tid >> 6, ln = tid & 63;
  const int bm = blockIdx.x, bn = blockIdx.y;
  const int wm = (w >> 1) * 64, wn = (w & 1) * 32;
  const f32x4 zf = {0.f, 0.f, 0.f, 0.f};
  f32x4 acc[4][2];
  #pragma unroll
  for (int i = 0; i < 4; i++)
    #pragma unroll
    for (int j = 0; j < 2; j++) acc[i][j] = zf;
  const int r8 = ln >> 3, s8 = ln & 7;
  for (int kt = 0; kt < K; kt += 64) {
    #pragma unroll
    for (int i = 0; i < 6; i++) {
      int jj = w * 6 + i;
      if (jj < 16) {
        gload16(A + (long)(bm * 128 + jj * 8 + r8) * K + kt + s8 * 8, &ldsA[jj * 512]);
      } else {
        int jb = jj - 16;
        gload16(Bt + (long)(bn * 64 + jb * 8 + r8) * K + kt + s8 * 8, &ldsB[jb * 512]);
      }
    }
    __syncthreads();
    #pragma unroll
    for (int kk = 0; kk < 2; kk++) {
      bf16x8 af[4], bfr[2];
      #pragma unroll
      for (int mf = 0; mf < 4; mf++)
        af[mf] = *(const bf16x8*)&ldsA[(wm + mf * 16 + (ln & 15)) * 64 + kk * 32 + (ln >> 4) * 8];
      #pragma unroll
      for (int nf = 0; nf < 2; nf++)
        bfr[nf] = *(const bf16x8*)&ldsB[(wn + nf * 16 + (ln & 15)) * 64 + kk * 32 + (ln >> 4) * 8];
      #pragma unroll
      for (int mf = 0; mf < 4; mf++)
        #pragma unroll
        for (int nf = 0; nf < 2; nf++)
          acc[mf][nf] = __builtin_amdgcn_mfma_f32_16x16x32_bf16(af[mf], bfr[nf], acc[mf][nf], 0, 0, 0);
    }
    __syncthreads();
  }
  const int g = ln >> 4, c = ln & 15;
  #pragma unroll
  for (int mf = 0; mf < 4; mf++) {
    #pragma unroll
    for (int nf = 0; nf < 2; nf++) {
      int col = bn * 64 + wn + nf * 16 + c;
      float bv = bias[col];
      #pragma unroll
      for (int j = 0; j < 4; j++) {
        long row = bm * 128 + wm + mf * 16 + g * 4 + j;
        float v = acc[mf][nf][j] + bv;
        if (EPI == 2) v = v > 0.f ? v : 0.f;
        if (EPI == 0)
          ((float*)Cv)[row * N + col] = v;
        else
          ((unsigned short*)Cv)[row * N + col] = bf16r(v);
      }
    }
  }
}

// ---------------- fused attention, split-K=2, 32x32 MFMA, in-register P ------
// Counted-vmcnt pipeline (T4): raw s_barrier + s_waitcnt vmcnt(2) keeps the
// next-tile global_load_lds in flight across barriers (no vmcnt(0) drain).
__global__ __launch_bounds__(256, 4) void attn_split_kernel(
    const unsigned short* __restrict__ qkv,
    const unsigned short* __restrict__ vt,
    const float* __restrict__ mask,
    unsigned short* __restrict__ opart,  // [2][32][2048][64] bf16 (unnormalized)
    float* __restrict__ lpart) {         // [2][32][2048] f32
  const int tid = threadIdx.x, w = tid >> 6, ln = tid & 63;
  const int lo = ln & 31, hi = ln >> 5;
  // XCD-aware bijective swizzle (1024 = 8 x 128)
  const int bid = blockIdx.x + 16 * blockIdx.y + 512 * blockIdx.z;
  const int swz = (bid & 7) * 128 + (bid >> 3);
  const int qb = swz & 15, bh = (swz >> 4) & 31, sp = swz >> 9;
  const int b = bh >> 3, h = bh & 7;
  const int q0 = qb * 128 + w * 32;
  const unsigned short* qp = qkv + (long)(b * 2048) * 1536 + h * 64;
  const unsigned short* kp = qp + 512;
  const unsigned short* vtp = vt + (long)bh * 64 * 2048;
  const float* mp = mask + b * 2048;

  __shared__ unsigned short kbuf[2][32 * 64];  // 4KB each
  __shared__ unsigned short vbuf[2][64 * 32];  // 4KB each

  const int jj0 = w * 2;
  auto stage = [&](int buf, int kt) {
    #pragma unroll
    for (int u = 0; u < 2; u++) {
      int jj = jj0 + u;
      if (jj < 4) {
        int r = jj * 8 + (ln >> 3);
        int s = ln & 7;
        gload16(kp + (long)(kt + r) * 1536 + ((s ^ (r & 7)) * 8),
                &kbuf[buf][jj * 512]);
      } else {
        int j = jj - 4;
        int r = j * 16 + (ln >> 2);
        int s = ln & 3;
        gload16(vtp + (long)r * 2048 + kt + ((s ^ ((r >> 1) & 3)) * 8),
                &vbuf[buf][j * 512]);
      }
    }
  };

  const int kt0 = sp * 1024;
  // block-uniform mask scan over this split's 1024 keys (hoisted out of loop)
  float mz = 0.f;
  #pragma unroll
  for (int i = 0; i < 16; i++) mz += fabsf(mp[kt0 + i * 64 + ln]);
  const bool anymask = __any(mz != 0.f);

  // Q fragments (B-operand, hoisted): Q[q0+lo][kdim t*16 + hi*8 .. +7]
  bf16x8 qf[4];
  #pragma unroll
  for (int t = 0; t < 4; t++)
    qf[t] = *(const bf16x8*)(qp + (long)(q0 + lo) * 1536 + t * 16 + hi * 8);

  f32x16 oacc[2];
  #pragma unroll
  for (int t = 0; t < 2; t++)
    #pragma unroll
    for (int r = 0; r < 16; r++) oacc[t][r] = 0.f;
  float lsum = 0.f;
  const f32x16 zf16 = oacc[0];

  stage(0, kt0);

  for (int it = 0; it < 32; it++) {
    const int kt = kt0 + it * 32;
    const int cur = it & 1;
    if (it + 1 < 32) {
      stage(cur ^ 1, kt + 32);
      asm volatile("s_waitcnt vmcnt(2)" ::: "memory");
    } else {
      asm volatile("s_waitcnt vmcnt(0)" ::: "memory");
    }
    __builtin_amdgcn_s_barrier();
    __builtin_amdgcn_sched_barrier(0);
    // QK^T: 4 MFMA over kdim
    f32x16 sacc = zf16;
    #pragma unroll
    for (int t = 0; t < 4; t++) {
      bf16x8 kf = *(const bf16x8*)&kbuf[cur][lo * 64 + (((t * 2 + hi) ^ (lo & 7)) * 8)];
      sacc = __builtin_amdgcn_mfma_f32_32x32x16_bf16(kf, qf[t], sacc, 0, 0, 0);
    }
    // softmax numerators (exp2 domain, folded 0.125*log2e)
    const float SC = 0.18033688011112042f;
    float e[16];
    #pragma unroll
    for (int r = 0; r < 16; r++) e[r] = sacc[r] * SC;
    if (anymask) {
      float mval = mp[kt + lo];
      #pragma unroll
      for (int r = 0; r < 16; r++)
        e[r] -= 1.4426950408889634e30f * __shfl(mval, (r & 3) + 8 * (r >> 2) + 4 * hi, 64);
    }
    #pragma unroll
    for (int r = 0; r < 16; r++) e[r] = __builtin_amdgcn_exp2f(e[r]);
    #pragma unroll
    for (int r = 0; r < 16; r++) lsum += e[r];
    // pack to bf16 pairs; assemble P^T fragments via half swaps
    unsigned int cv[8];
    #pragma unroll
    for (int i = 0; i < 8; i++) cv[i] = pkbf16(e[2 * i], e[2 * i + 1]);
    #pragma unroll
    for (int stt = 0; stt < 2; stt++) {
      unsigned int pf[4];
#if __has_builtin(__builtin_amdgcn_permlane32_swap)
      {
        auto r0 = __builtin_amdgcn_permlane32_swap(cv[stt * 4 + 0], cv[stt * 4 + 2], false, false);
        auto r1 = __builtin_amdgcn_permlane32_swap(cv[stt * 4 + 1], cv[stt * 4 + 3], false, false);
        pf[0] = r0[0]; pf[1] = r1[0]; pf[2] = r0[1]; pf[3] = r1[1];
      }
#else
      {
        unsigned int c0 = cv[stt * 4 + 0], c1 = cv[stt * 4 + 1];
        unsigned int c2 = cv[stt * 4 + 2], c3 = cv[stt * 4 + 3];
        unsigned int s0 = __shfl_xor(c0, 32, 64), s1 = __shfl_xor(c1, 32, 64);
        unsigned int s2 = __shfl_xor(c2, 32, 64), s3 = __shfl_xor(c3, 32, 64);
        pf[0] = hi ? s2 : c0;
        pf[1] = hi ? s3 : c1;
        pf[2] = hi ? c2 : s0;
        pf[3] = hi ? c3 : s1;
      }
#endif
      bf16x8 pfr = *(const bf16x8*)pf;
      #pragma unroll
      for (int tau = 0; tau < 2; tau++) {
        int vr = tau * 32 + lo;
        bf16x8 vf = *(const bf16x8*)&vbuf[cur][vr * 32 + ((((stt * 2 + hi) ^ ((vr >> 1) & 3))) * 8)];
        oacc[tau] = __builtin_amdgcn_mfma_f32_32x32x16_bf16(vf, pfr, oacc[tau], 0, 0, 0);
      }
    }
    __builtin_amdgcn_sched_barrier(0);
    __builtin_amdgcn_s_barrier();   // all waves done reading cur before overwrite
  }
  lsum += __shfl_xor(lsum, 32, 64);
  unsigned short* ob = opart + (long)(sp * 32 + bh) * 2048 * 64;
  const long row = q0 + lo;
  #pragma unroll
  for (int tau = 0; tau < 2; tau++) {
    #pragma unroll
    for (int j = 0; j < 4; j++) {
      ushort4 o;
      o.x = bf16r(oacc[tau][4 * j + 0]);
      o.y = bf16r(oacc[tau][4 * j + 1]);
      o.z = bf16r(oacc[tau][4 * j + 2]);
      o.w = bf16r(oacc[tau][4 * j + 3]);
      *(ushort4*)(ob + row * 64 + tau * 32 + j * 8 + hi * 4) = o;
    }
  }
  if (hi == 0)
    lpart[(long)(sp * 32 + bh) * 2048 + row] = lsum;
}

// ---------------- combine split-K partials -> ao (bf16) ----------------------
__global__ __launch_bounds__(256) void attn_combine(const unsigned short* __restrict__ opart,
                                                    const float* __restrict__ lpart,
                                                    unsigned short* __restrict__ ao) {
  const long row = blockIdx.x;           // b*2048 + q
  const int b = (int)(row >> 11), q = (int)(row & 2047);
  #pragma unroll
  for (int half = 0; half < 2; half++) {
    int col = threadIdx.x + half * 256;
    int h = col >> 6, hd = col & 63;
    int bh = b * 8 + h;
    float l = lpart[(long)bh * 2048 + q] + lpart[(long)(32 + bh) * 2048 + q];
    long i0 = ((long)bh * 2048 + q) * 64 + hd;
    long i1 = ((long)(32 + bh) * 2048 + q) * 64 + hd;
    float v = (bf2f(opart[i0]) + bf2f(opart[i1])) / l;
    ao[row * 512 + col] = bf16r(v);
  }
}

// ---------------- layernorm rows, fp32 in; OUTF 0 = bf16 out, 1 = f32 out ----
template <int OUTF>
__global__ __launch_bounds__(256) void ln_kernel(const float* __restrict__ in,
                                                 const float* __restrict__ gam,
                                                 const float* __restrict__ bet,
                                                 void* __restrict__ out) {
  const long row = blockIdx.x;
  const float* x = in + row * 512;
  float v0 = x[threadIdx.x], v1 = x[threadIdx.x + 256];
  float s = v0 + v1, ss = v0 * v0 + v1 * v1;
  #pragma unroll
  for (int off = 32; off > 0; off >>= 1) {
    s += __shfl_down(s, off, 64);
    ss += __shfl_down(ss, off, 64);
  }
  __shared__ float red[8];
  __shared__ float mv[2];
  int w = threadIdx.x >> 6, ln = threadIdx.x & 63;
  if (ln == 0) { red[w] = s; red[w + 4] = ss; }
  __syncthreads();
  if (threadIdx.x == 0) {
    float S = red[0] + red[1] + red[2] + red[3];
    float SS = red[4] + red[5] + red[6] + red[7];
    float mu = S * (1.f / 512.f);
    float var = SS * (1.f / 512.f) - mu * mu;
    mv[0] = mu;
    mv[1] = rsqrtf(var + 1e-5f);
  }
  __syncthreads();
  float mu = mv[0], rs = mv[1];
  float o0 = (v0 - mu) * rs * gam[threadIdx.x] + bet[threadIdx.x];
  float o1 = (v1 - mu) * rs * gam[threadIdx.x + 256] + bet[threadIdx.x + 256];
  if (OUTF == 0) {
    ((unsigned short*)out)[row * 512 + threadIdx.x] = bf16r(o0);
    ((unsigned short*)out)[row * 512 + threadIdx.x + 256] = bf16r(o1);
  } else {
    ((float*)out)[row * 512 + threadIdx.x] = o0;
    ((float*)out)[row * 512 + threadIdx.x + 256] = o1;
  }
}

// ---------------- pool: alpha = leaky_relu(h @ pw + pb) + mask*-1e16 ---------
__global__ __launch_bounds__(256) void alpha_kernel(const float* __restrict__ h,
                                                    const float* __restrict__ pw,
                                                    const float* __restrict__ pbias,
                                                    const float* __restrict__ mask,
                                                    float* __restrict__ alpha) {
  int w = threadIdx.x >> 6, ln = threadIdx.x & 63;
  long row = (long)blockIdx.x * 4 + w;
  float p[8];
  #pragma unroll
  for (int k = 0; k < 8; k++) p[k] = 0.f;
  #pragma unroll
  for (int it = 0; it < 8; it++) {
    int d = it * 64 + ln;
    float xv = h[row * 512 + d];
    const float* wr = pw + d * 8;
    #pragma unroll
    for (int k = 0; k < 8; k++) p[k] += xv * wr[k];
  }
  #pragma unroll
  for (int off = 32; off > 0; off >>= 1)
    #pragma unroll
    for (int k = 0; k < 8; k++) p[k] += __shfl_down(p[k], off, 64);
  if (ln == 0) {
    float mterm = mask[row] * (-1e16f);
    #pragma unroll
    for (int k = 0; k < 8; k++) {
      float a = p[k] + pbias[k];
      a = a < 0.f ? 0.01f * a : a;
      alpha[row * 8 + k] = a + mterm;
    }
  }
}

__global__ __launch_bounds__(256) void stats_kernel(const float* __restrict__ alpha,
                                                    float* __restrict__ stats) {
  int b = blockIdx.x >> 3, ph = blockIdx.x & 7;
  const float* a = alpha + (long)b * 2048 * 8 + ph;
  __shared__ float rr[4];
  __shared__ float mm[1];
  int w = threadIdx.x >> 6, ln = threadIdx.x & 63;
  float m = -1e38f;
  for (int s = threadIdx.x; s < 2048; s += 256) m = fmaxf(m, a[(long)s * 8]);
  #pragma unroll
  for (int off = 32; off > 0; off >>= 1) m = fmaxf(m, __shfl_down(m, off, 64));
  if (ln == 0) rr[w] = m;
  __syncthreads();
  if (threadIdx.x == 0) mm[0] = fmaxf(fmaxf(rr[0], rr[1]), fmaxf(rr[2], rr[3]));
  __syncthreads();
  float M = mm[0];
  float sum = 0.f;
  for (int s = threadIdx.x; s < 2048; s += 256) sum += __expf(a[(long)s * 8] - M);
  #pragma unroll
  for (int off = 32; off > 0; off >>= 1) sum += __shfl_down(sum, off, 64);
  __syncthreads();
  if (ln == 0) rr[w] = sum;
  __syncthreads();
  if (threadIdx.x == 0) {
    stats[blockIdx.x * 2] = M;
    stats[blockIdx.x * 2 + 1] = rr[0] + rr[1] + rr[2] + rr[3];
  }
}

// partial[sc + b*8][d] = sum over its 256-seq chunk of w(s) * h[s][d]
__global__ __launch_bounds__(256) void pool_kernel(const float* __restrict__ h,
                                                   const float* __restrict__ alpha,
                                                   const float* __restrict__ stats,
                                                   float* __restrict__ partial) {
  int b = blockIdx.x >> 3, sc = blockIdx.x & 7;
  int s0 = sc * 256;
  __shared__ float wb[256];
  {
    long s = s0 + threadIdx.x;
    const float* a = alpha + ((long)b * 2048 + s) * 8;
    float wsum = 0.f;
    #pragma unroll
    for (int ph = 0; ph < 8; ph++) {
      float M = stats[(b * 8 + ph) * 2], Sm = stats[(b * 8 + ph) * 2 + 1];
      wsum += __expf(a[ph] - M) / Sm;
    }
    wb[threadIdx.x] = wsum;
  }
  __syncthreads();
  float a0 = 0.f, a1 = 0.f;
  const float* hb = h + ((long)b * 2048 + s0) * 512;
  for (int i = 0; i < 256; i++) {
    float wv = wb[i];
    a0 += wv * hb[(long)i * 512 + threadIdx.x];
    a1 += wv * hb[(long)i * 512 + threadIdx.x + 256];
  }
  partial[(long)blockIdx.x * 512 + threadIdx.x] = a0;
  partial[(long)blockIdx.x * 512 + threadIdx.x + 256] = a1;
}

__global__ __launch_bounds__(256) void pool_final(const float* __restrict__ partial,
                                                  float* __restrict__ out) {
  int b = blockIdx.x;
  float a0 = 0.f, a1 = 0.f;
  #pragma unroll
  for (int sc = 0; sc < 8; sc++) {
    a0 += partial[(long)(b * 8 + sc) * 512 + threadIdx.x];
    a1 += partial[(long)(b * 8 + sc) * 512 + threadIdx.x + 256];
  }
  out[b * 512 + threadIdx.x] = a0;
  out[b * 512 + threadIdx.x + 256] = a1;
}

// -----------------------------------------------------------------------------
extern "C" void kernel_launch(void* const* d_in, const int* in_sizes, int n_in,
                              void* d_out, int out_size, void* d_ws, size_t ws_size,
                              hipStream_t stream) {
  (void)in_sizes; (void)n_in; (void)out_size;
  if (ws_size < 92274688UL) return;  // need ~88MB scratch

  const float* x    = (const float*)d_in[0];
  const float* mask = (const float*)d_in[1];
  const float* q1w = (const float*)d_in[2];  const float* q1b = (const float*)d_in[3];
  const float* k1w = (const float*)d_in[4];  const float* k1b = (const float*)d_in[5];
  const float* v1w = (const float*)d_in[6];  const float* v1b = (const float*)d_in[7];
  const float* o1w = (const float*)d_in[8];  const float* o1b = (const float*)d_in[9];
  const float* q2w = (const float*)d_in[10]; const float* q2b = (const float*)d_in[11];
  const float* k2w = (const float*)d_in[12]; const float* k2b = (const float*)d_in[13];
  const float* v2w = (const float*)d_in[14]; const float* v2b = (const float*)d_in[15];
  const float* o2w = (const float*)d_in[16]; const float* o2b = (const float*)d_in[17];
  const float* ln1g = (const float*)d_in[18]; const float* ln1b = (const float*)d_in[19];
  const float* fw1 = (const float*)d_in[20]; const float* fb1 = (const float*)d_in[21];
  const float* fw2 = (const float*)d_in[22]; const float* fb2 = (const float*)d_in[23];
  const float* ln2g = (const float*)d_in[24]; const float* ln2b = (const float*)d_in[25];
  const float* poolw = (const float*)d_in[26]; const float* poolb = (const float*)d_in[27];

  char* ws = (char*)d_ws;
  unsigned short* Wt  = (unsigned short*)(ws + 0);          // 10 x 512x512 bf16 (5MB)
  float* qb1          = (float*)(ws + 5242880);
  float* qb2          = (float*)(ws + 5249024);
  float* stats        = (float*)(ws + 5255168);
  float* alpha        = (float*)(ws + 5255424);             // 256KB
  float* partial      = (float*)(ws + 5517568);             // 64KB
  unsigned short* qkv = (unsigned short*)(ws + 8388608);    // [8192][1536] bf16 (24MB)
  unsigned short* vt  = (unsigned short*)(ws + 33554432);   // [32][64][2048] bf16 (8MB)
  unsigned short* ao  = (unsigned short*)(ws + 41943040);   // [8192][512] bf16 (8MB)
  float* t            = (float*)(ws + 50331648);            // [8192][512] f32 (16MB)
  unsigned short* xn  = (unsigned short*)(ws + 67108864);   // [8192][512] bf16 (8MB)
  unsigned short* h1  = (unsigned short*)(ws + 75497472);   // (8MB)
  unsigned short* f   = (unsigned short*)(ws + 83886080);   // (8MB)
  unsigned short* h2  = xn;                                 // xn dead by then
  // attention split-K partials: live ONLY during attn+combine; [t] is dead then.
  unsigned short* opart = (unsigned short*)(ws + 50331648); // 16.8MB [2][32][2048][64] bf16
  float* lpart          = (float*)(ws + 83886080);          // 512KB [2][32][2048] (dead f)

  PrepArgs pa;
  pa.w[0] = q1w; pa.w[1] = k1w; pa.w[2] = v1w; pa.w[3] = o1w; pa.w[4] = fw1;
  pa.w[5] = fw2; pa.w[6] = q2w; pa.w[7] = k2w; pa.w[8] = v2w; pa.w[9] = o2w;
  pa.b1[0] = q1b; pa.b1[1] = k1b; pa.b1[2] = v1b;
  pa.b2[0] = q2b; pa.b2[1] = k2b; pa.b2[2] = v2b;

  prep_kernel<<<dim3(8, 8, 10), 256, 0, stream>>>(pa, Wt, qb1, qb2);
  l2norm_kernel<<<8192, 256, 0, stream>>>(x, xn);

  // layer 1 (QKV GEMM writes V directly transposed into vt)
  gemm_bt<3><<<dim3(64, 12), 256, 0, stream>>>(xn, Wt, qb1, qkv, 512, 1536, vt);
  attn_split_kernel<<<dim3(16, 32, 2), 256, 0, stream>>>(qkv, vt, mask, opart, lpart);
  attn_combine<<<8192, 256, 0, stream>>>(opart, lpart, ao);
  gemm_bt64<0><<<dim3(64, 8), 256, 0, stream>>>(ao, Wt + 3L * 512 * 512, o1b, t, 512, 512);
  ln_kernel<0><<<8192, 256, 0, stream>>>(t, ln1g, ln1b, h1);
  gemm_bt64<2><<<dim3(64, 8), 256, 0, stream>>>(h1, Wt + 4L * 512 * 512, fb1, f, 512, 512);
  gemm_bt64<1><<<dim3(64, 8), 256, 0, stream>>>(f, Wt + 5L * 512 * 512, fb2, h2, 512, 512);

  // layer 2
  gemm_bt<3><<<dim3(64, 12), 256, 0, stream>>>(h2, Wt + 6L * 512 * 512, qb2, qkv, 512, 1536, vt);
  attn_split_kernel<<<dim3(16, 32, 2), 256, 0, stream>>>(qkv, vt, mask, opart, lpart);
  attn_combine<<<8192, 256, 0, stream>>>(opart, lpart, ao);
  gemm_bt64<0><<<dim3(64, 8), 256, 0, stream>>>(ao, Wt + 9L * 512 * 512, o2b, t, 512, 512);
  ln_kernel<1><<<8192, 256, 0, stream>>>(t, ln2g, ln2b, t);  // in-place f32

  // pooling
  alpha_kernel<<<2048, 256, 0, stream>>>(t, poolw, poolb, mask, alpha);
  stats_kernel<<<32, 256, 0, stream>>>(alpha, stats);
  pool_kernel<<<32, 256, 0, stream>>>(t, alpha, stats, partial);
  pool_final<<<4, 256, 0, stream>>>(partial, (float*)d_out);
}

// Round 12
// 297.915 us; speedup vs baseline: 1.0301x; 1.0187x over previous
//
#include <hip/hip_runtime.h>
#include <hip/hip_bf16.h>
#include <stdint.h>

#define DEVI __device__ __forceinline__

typedef float f32x4 __attribute__((ext_vector_type(4)));
typedef float f32x16 __attribute__((ext_vector_type(16)));
typedef short bf16x8 __attribute__((ext_vector_type(8)));

typedef __attribute__((address_space(3))) unsigned int as3_u32;
typedef __attribute__((address_space(1))) unsigned int as1_u32;

DEVI void gload16(const void* g, void* l) {
  __builtin_amdgcn_global_load_lds((const as1_u32*)g, (as3_u32*)l, 16, 0, 0);
}

DEVI unsigned short bf16r(float f) {
  union { float f; unsigned int u; } v; v.f = f;
  unsigned int u = v.u;
  return (unsigned short)((u + 0x7FFFu + ((u >> 16) & 1u)) >> 16);
}

DEVI float bf2f(unsigned short u) {
  unsigned int x = ((unsigned int)u) << 16;
  union { unsigned int u; float f; } v; v.u = x;
  return v.f;
}

DEVI unsigned int pkbf16(float a, float b) {
  __hip_bfloat162 h = __float22bfloat162_rn(make_float2(a, b));
  return *(unsigned int*)&h;
}

// ---------------- weight prep: fp32 [K][N] -> bf16 [N][K], pack qkv biases ----
struct PrepArgs {
  const float* w[10];
  const float* b1[3];
  const float* b2[3];
};

__global__ __launch_bounds__(256) void prep_kernel(PrepArgs pa, unsigned short* wt,
                                                   float* qb1, float* qb2) {
  __shared__ float lt[64][65];
  const int slot = blockIdx.z;
  const int n0 = blockIdx.x * 64, k0 = blockIdx.y * 64;
  const float* W = pa.w[slot];
  for (int it = 0; it < 16; it++) {
    int idx = it * 256 + threadIdx.x;
    int kr = idx >> 6, nc = idx & 63;
    lt[kr][nc] = W[(long)(k0 + kr) * 512 + n0 + nc];
  }
  __syncthreads();
  unsigned short* dst = wt + (long)slot * 512 * 512;
  for (int it = 0; it < 16; it++) {
    int idx = it * 256 + threadIdx.x;
    int nr = idx >> 6, kc = idx & 63;
    dst[(long)(n0 + nr) * 512 + k0 + kc] = bf16r(lt[kc][nr]);
  }
  if (blockIdx.x == 0 && blockIdx.y == 0) {
    if (slot < 3) {
      for (int i = threadIdx.x; i < 512; i += 256) qb1[slot * 512 + i] = pa.b1[slot][i];
    } else if (slot >= 6 && slot < 9) {
      for (int i = threadIdx.x; i < 512; i += 256) qb2[(slot - 6) * 512 + i] = pa.b2[slot - 6][i];
    }
  }
}

// ---------------- l2 normalize rows of x, fp32 -> bf16 -----------------------
__global__ __launch_bounds__(256) void l2norm_kernel(const float* __restrict__ x,
                                                     unsigned short* __restrict__ xn) {
  const long row = blockIdx.x;
  const float* xr = x + row * 512;
  float v0 = xr[threadIdx.x], v1 = xr[threadIdx.x + 256];
  float ss = v0 * v0 + v1 * v1;
  #pragma unroll
  for (int off = 32; off > 0; off >>= 1) ss += __shfl_down(ss, off, 64);
  __shared__ float red[4];
  __shared__ float sc[1];
  int w = threadIdx.x >> 6, ln = threadIdx.x & 63;
  if (ln == 0) red[w] = ss;
  __syncthreads();
  if (threadIdx.x == 0) {
    float S = red[0] + red[1] + red[2] + red[3];
    sc[0] = 1.0f / fmaxf(sqrtf(S), 1e-12f);
  }
  __syncthreads();
  float s = sc[0];
  xn[row * 512 + threadIdx.x] = bf16r(v0 * s);
  xn[row * 512 + threadIdx.x + 256] = bf16r(v1 * s);
}

// ---------------- GEMM 128x128: C = A x Bt^T + bias --------------------------
// EPI: 0 = f32 out, 1 = bf16 out, 2 = bf16 out + relu,
//      3 = bf16 out; cols >=1024 are V -> written transposed into vtout
template <int EPI>
__global__ __launch_bounds__(256) void gemm_bt(const unsigned short* __restrict__ A,
                                               const unsigned short* __restrict__ Bt,
                                               const float* __restrict__ bias,
                                               void* __restrict__ Cv, int K, int N,
                                               unsigned short* __restrict__ vtout) {
  __shared__ unsigned short ldsA[128 * 64];
  __shared__ unsigned short ldsB[128 * 64];
  const int tid = threadIdx.x, w = tid >> 6, ln = tid & 63;
  const int bm = blockIdx.x, bn = blockIdx.y;
  const int wm = (w >> 1) * 64, wn = (w & 1) * 64;
  const f32x4 zf = {0.f, 0.f, 0.f, 0.f};
  f32x4 acc[4][4];
  #pragma unroll
  for (int i = 0; i < 4; i++)
    #pragma unroll
    for (int j = 0; j < 4; j++) acc[i][j] = zf;
  const int r8 = ln >> 3, s8 = ln & 7;
  for (int kt = 0; kt < K; kt += 64) {
    #pragma unroll
    for (int i = 0; i < 4; i++) {
      int row = w * 32 + i * 8 + r8;
      gload16(A + (long)(bm * 128 + row) * K + kt + s8 * 8, &ldsA[(w * 32 + i * 8) * 64]);
      gload16(Bt + (long)(bn * 128 + row) * K + kt + s8 * 8, &ldsB[(w * 32 + i * 8) * 64]);
    }
    __syncthreads();
    #pragma unroll
    for (int kk = 0; kk < 2; kk++) {
      bf16x8 af[4], bfr[4];
      #pragma unroll
      for (int mf = 0; mf < 4; mf++) {
        int row = wm + mf * 16 + (ln & 15);
        af[mf] = *(const bf16x8*)&ldsA[row * 64 + kk * 32 + (ln >> 4) * 8];
      }
      #pragma unroll
      for (int nf = 0; nf < 4; nf++) {
        int row = wn + nf * 16 + (ln & 15);
        bfr[nf] = *(const bf16x8*)&ldsB[row * 64 + kk * 32 + (ln >> 4) * 8];
      }
      #pragma unroll
      for (int mf = 0; mf < 4; mf++)
        #pragma unroll
        for (int nf = 0; nf < 4; nf++)
          acc[mf][nf] = __builtin_amdgcn_mfma_f32_16x16x32_bf16(af[mf], bfr[nf], acc[mf][nf], 0, 0, 0);
    }
    __syncthreads();
  }
  const int g = ln >> 4, c = ln & 15;
  #pragma unroll
  for (int mf = 0; mf < 4; mf++) {
    #pragma unroll
    for (int nf = 0; nf < 4; nf++) {
      int col = bn * 128 + wn + nf * 16 + c;
      float bv = bias[col];
      if (EPI == 3 && col >= 1024) {
        long row0 = bm * 128 + wm + mf * 16 + g * 4;
        int b = (int)(row0 >> 11), s = (int)(row0 & 2047);
        int vc = col - 1024, h = vc >> 6, hd = vc & 63;
        ushort4 o;
        o.x = bf16r(acc[mf][nf][0] + bv);
        o.y = bf16r(acc[mf][nf][1] + bv);
        o.z = bf16r(acc[mf][nf][2] + bv);
        o.w = bf16r(acc[mf][nf][3] + bv);
        *(ushort4*)(vtout + ((long)((b * 8 + h) * 64 + hd)) * 2048 + s) = o;
      } else {
        #pragma unroll
        for (int j = 0; j < 4; j++) {
          long row = bm * 128 + wm + mf * 16 + g * 4 + j;
          float v = acc[mf][nf][j] + bv;
          if (EPI == 2) v = v > 0.f ? v : 0.f;
          if (EPI == 0)
            ((float*)Cv)[row * N + col] = v;
          else
            ((unsigned short*)Cv)[row * N + col] = bf16r(v);
        }
      }
    }
  }
}

// ---------------- GEMM 128x64 tile (for N=512 chains: 512 blocks, 2/CU) ------
template <int EPI>
__global__ __launch_bounds__(256) void gemm_bt64(const unsigned short* __restrict__ A,
                                                 const unsigned short* __restrict__ Bt,
                                                 const float* __restrict__ bias,
                                                 void* __restrict__ Cv, int K, int N) {
  __shared__ unsigned short ldsA[128 * 64];
  __shared__ unsigned short ldsB[64 * 64];
  const int tid = threadIdx.x, w = tid >> 6, ln = tid & 63;
  const int bm = blockIdx.x, bn = blockIdx.y;
  const int wm = (w >> 1) * 64, wn = (w & 1) * 32;
  const f32x4 zf = {0.f, 0.f, 0.f, 0.f};
  f32x4 acc[4][2];
  #pragma unroll
  for (int i = 0; i < 4; i++)
    #pragma unroll
    for (int j = 0; j < 2; j++) acc[i][j] = zf;
  const int r8 = ln >> 3, s8 = ln & 7;
  for (int kt = 0; kt < K; kt += 64) {
    #pragma unroll
    for (int i = 0; i < 6; i++) {
      int jj = w * 6 + i;
      if (jj < 16) {
        gload16(A + (long)(bm * 128 + jj * 8 + r8) * K + kt + s8 * 8, &ldsA[jj * 512]);
      } else {
        int jb = jj - 16;
        gload16(Bt + (long)(bn * 64 + jb * 8 + r8) * K + kt + s8 * 8, &ldsB[jb * 512]);
      }
    }
    __syncthreads();
    #pragma unroll
    for (int kk = 0; kk < 2; kk++) {
      bf16x8 af[4], bfr[2];
      #pragma unroll
      for (int mf = 0; mf < 4; mf++)
        af[mf] = *(const bf16x8*)&ldsA[(wm + mf * 16 + (ln & 15)) * 64 + kk * 32 + (ln >> 4) * 8];
      #pragma unroll
      for (int nf = 0; nf < 2; nf++)
        bfr[nf] = *(const bf16x8*)&ldsB[(wn + nf * 16 + (ln & 15)) * 64 + kk * 32 + (ln >> 4) * 8];
      #pragma unroll
      for (int mf = 0; mf < 4; mf++)
        #pragma unroll
        for (int nf = 0; nf < 2; nf++)
          acc[mf][nf] = __builtin_amdgcn_mfma_f32_16x16x32_bf16(af[mf], bfr[nf], acc[mf][nf], 0, 0, 0);
    }
    __syncthreads();
  }
  const int g = ln >> 4, c = ln & 15;
  #pragma unroll
  for (int mf = 0; mf < 4; mf++) {
    #pragma unroll
    for (int nf = 0; nf < 2; nf++) {
      int col = bn * 64 + wn + nf * 16 + c;
      float bv = bias[col];
      #pragma unroll
      for (int j = 0; j < 4; j++) {
        long row = bm * 128 + wm + mf * 16 + g * 4 + j;
        float v = acc[mf][nf][j] + bv;
        if (EPI == 2) v = v > 0.f ? v : 0.f;
        if (EPI == 0)
          ((float*)Cv)[row * N + col] = v;
        else
          ((unsigned short*)Cv)[row * N + col] = bf16r(v);
      }
    }
  }
}

// ---------------- fused attention, split-K=4, 32x32 MFMA, in-register P ------
// VALU-lean body: LDS read offsets hoisted (loop-invariant), 2x unroll makes
// buffer base compile-time; staging pointers strength-reduced (+const stride);
// mask staged in LDS (no in-loop global loads -> clean vmcnt counting).
__global__ __launch_bounds__(256, 4) void attn_split_kernel(
    const unsigned short* __restrict__ qkv,
    const unsigned short* __restrict__ vt,
    const float* __restrict__ mask,
    unsigned short* __restrict__ opart,  // [4][32][2048][64] bf16 (unnormalized)
    float* __restrict__ lpart) {         // [4][32][2048] f32
  const int tid = threadIdx.x, w = tid >> 6, ln = tid & 63;
  const int lo = ln & 31, hi = ln >> 5;
  // XCD-aware bijective swizzle (2048 = 8 x 256)
  const int bid = blockIdx.x + 16 * blockIdx.y + 512 * blockIdx.z;
  const int swz = (bid & 7) * 256 + (bid >> 3);
  const int qb = swz & 15, bh = (swz >> 4) & 31, sp = swz >> 9;
  const int b = bh >> 3, h = bh & 7;
  const int q0 = qb * 128 + w * 32;
  const unsigned short* qp = qkv + (long)(b * 2048) * 1536 + h * 64;
  const unsigned short* kp = qp + 512;
  const unsigned short* vtp = vt + (long)bh * 64 * 2048;
  const float* mp = mask + b * 2048;
  const int kt0 = sp * 512;

  // K region: elements [0,2048) = 32 rows x 64; V region: [2048,4096) = 64 rows x 32
  __shared__ unsigned short sbuf[2][4096];   // 8KB per buffer
  __shared__ float mbuf[512];
  __shared__ int mflag;

  // ---- mask -> LDS, block-uniform anymask flag
  {
    float mv0 = mp[kt0 + tid], mv1 = mp[kt0 + 256 + tid];
    mbuf[tid] = mv0;
    mbuf[tid + 256] = mv1;
    if (tid == 0) mflag = 0;
    __syncthreads();
    if (mv0 != 0.f || mv1 != 0.f) mflag = 1;
    __syncthreads();
  }
  const bool anymask = (mflag != 0);

  // ---- staging: per-wave 2 chunks; pointers strength-reduced
  const int jj0 = w * 2;
  const char *src0, *src1;
  long step;
  if (w < 2) {  // K chunks jj0, jj0+1 (rows 8 apart)
    int r0 = jj0 * 8 + (ln >> 3), r1 = r0 + 8, s = ln & 7;
    src0 = (const char*)kp + 2L * ((long)(kt0 + r0) * 1536 + ((s ^ (r0 & 7)) * 8));
    src1 = (const char*)kp + 2L * ((long)(kt0 + r1) * 1536 + ((s ^ (r1 & 7)) * 8));
    step = 32L * 1536 * 2;
  } else {      // V chunks j0, j0+1 (hd rows 16 apart)
    int j0 = (w - 2) * 2;
    int r0 = j0 * 16 + (ln >> 2), r1 = r0 + 16, s = ln & 3;
    src0 = (const char*)vtp + 2L * ((long)r0 * 2048 + kt0 + ((s ^ ((r0 >> 1) & 3)) * 8));
    src1 = (const char*)vtp + 2L * ((long)r1 * 2048 + kt0 + ((s ^ ((r1 >> 1) & 3)) * 8));
    step = 64;
  }
  unsigned short* const d0a = &sbuf[0][jj0 * 512];
  unsigned short* const d0b = d0a + 512;
  unsigned short* const d1a = &sbuf[1][jj0 * 512];
  unsigned short* const d1b = d1a + 512;

  // ---- loop-invariant LDS read offsets (elements)
  int koffe[4];
  #pragma unroll
  for (int t = 0; t < 4; t++)
    koffe[t] = lo * 64 + (((t * 2 + hi) ^ (lo & 7)) * 8);
  int voffe[4];
  #pragma unroll
  for (int stt = 0; stt < 2; stt++)
    #pragma unroll
    for (int tau = 0; tau < 2; tau++) {
      int vr = tau * 32 + lo;
      voffe[stt * 2 + tau] = 2048 + vr * 32 + ((((stt * 2 + hi) ^ ((vr >> 1) & 3))) * 8);
    }

  // ---- Q fragments (B-operand, hoisted)
  bf16x8 qf[4];
  #pragma unroll
  for (int t = 0; t < 4; t++)
    qf[t] = *(const bf16x8*)(qp + (long)(q0 + lo) * 1536 + t * 16 + hi * 8);

  f32x16 oacc[2];
  #pragma unroll
  for (int t = 0; t < 2; t++)
    #pragma unroll
    for (int r = 0; r < 16; r++) oacc[t][r] = 0.f;
  float lsum = 0.f;
  const f32x16 zf16 = oacc[0];
  const float SC = 0.18033688011112042f;  // 0.125 * log2(e)

  // prologue stage into buf0
  gload16(src0, d0a);
  gload16(src1, d0b);
  src0 += step; src1 += step;

#define ATTN_BODY(CURB, DA, DB, ITOFF, STAGE_NEXT)                              \
  {                                                                             \
    if (STAGE_NEXT) {                                                           \
      gload16(src0, DA);                                                        \
      gload16(src1, DB);                                                        \
      src0 += step; src1 += step;                                               \
      asm volatile("s_waitcnt vmcnt(2)" ::: "memory");                          \
    } else {                                                                    \
      asm volatile("s_waitcnt vmcnt(0)" ::: "memory");                          \
    }                                                                           \
    __builtin_amdgcn_s_barrier();                                               \
    __builtin_amdgcn_sched_barrier(0);                                          \
    f32x16 sacc = zf16;                                                         \
    _Pragma("unroll")                                                           \
    for (int t = 0; t < 4; t++) {                                               \
      bf16x8 kf = *(const bf16x8*)&sbuf[CURB][koffe[t]];                        \
      sacc = __builtin_amdgcn_mfma_f32_32x32x16_bf16(kf, qf[t], sacc, 0, 0, 0); \
    }                                                                           \
    float e[16];                                                                \
    _Pragma("unroll")                                                           \
    for (int r = 0; r < 16; r++) e[r] = sacc[r] * SC;                           \
    if (anymask) {                                                              \
      float mval = mbuf[(ITOFF) + lo];                                          \
      _Pragma("unroll")                                                         \
      for (int r = 0; r < 16; r++)                                              \
        e[r] -= 1.4426950408889634e30f *                                        \
                __shfl(mval, (r & 3) + 8 * (r >> 2) + 4 * hi, 64);              \
    }                                                                           \
    _Pragma("unroll")                                                           \
    for (int r = 0; r < 16; r++) e[r] = __builtin_amdgcn_exp2f(e[r]);           \
    _Pragma("unroll")                                                           \
    for (int r = 0; r < 16; r++) lsum += e[r];                                  \
    unsigned int cv[8];                                                         \
    _Pragma("unroll")                                                           \
    for (int i = 0; i < 8; i++) cv[i] = pkbf16(e[2 * i], e[2 * i + 1]);         \
    _Pragma("unroll")                                                           \
    for (int stt = 0; stt < 2; stt++) {                                         \
      unsigned int pf[4];                                                       \
      {                                                                         \
        auto r0_ = __builtin_amdgcn_permlane32_swap(cv[stt * 4 + 0],            \
                                                    cv[stt * 4 + 2], false, false); \
        auto r1_ = __builtin_amdgcn_permlane32_swap(cv[stt * 4 + 1],            \
                                                    cv[stt * 4 + 3], false, false); \
        pf[0] = r0_[0]; pf[1] = r1_[0]; pf[2] = r0_[1]; pf[3] = r1_[1];         \
      }                                                                         \
      bf16x8 pfr = *(const bf16x8*)pf;                                          \
      _Pragma("unroll")                                                         \
      for (int tau = 0; tau < 2; tau++) {                                       \
        bf16x8 vf = *(const bf16x8*)&sbuf[CURB][voffe[stt * 2 + tau]];          \
        oacc[tau] = __builtin_amdgcn_mfma_f32_32x32x16_bf16(vf, pfr, oacc[tau], 0, 0, 0); \
      }                                                                         \
    }                                                                           \
    __builtin_amdgcn_sched_barrier(0);                                          \
    __builtin_amdgcn_s_barrier();                                               \
  }

  for (int it2 = 0; it2 < 8; it2++) {
    ATTN_BODY(0, d1a, d1b, it2 * 64, 1)
    ATTN_BODY(1, d0a, d0b, it2 * 64 + 32, (it2 < 7))
  }
#undef ATTN_BODY

  lsum += __shfl_xor(lsum, 32, 64);
  unsigned short* ob = opart + (long)(sp * 32 + bh) * 2048 * 64;
  const long row = q0 + lo;
  #pragma unroll
  for (int tau = 0; tau < 2; tau++) {
    #pragma unroll
    for (int j = 0; j < 4; j++) {
      ushort4 o;
      o.x = bf16r(oacc[tau][4 * j + 0]);
      o.y = bf16r(oacc[tau][4 * j + 1]);
      o.z = bf16r(oacc[tau][4 * j + 2]);
      o.w = bf16r(oacc[tau][4 * j + 3]);
      *(ushort4*)(ob + row * 64 + tau * 32 + j * 8 + hi * 4) = o;
    }
  }
  if (hi == 0)
    lpart[(long)(sp * 32 + bh) * 2048 + row] = lsum;
}

// ---------------- combine split-K partials -> ao (bf16) ----------------------
__global__ __launch_bounds__(256) void attn_combine(const unsigned short* __restrict__ opart,
                                                    const float* __restrict__ lpart,
                                                    unsigned short* __restrict__ ao) {
  const long row = blockIdx.x;           // b*2048 + q
  const int b = (int)(row >> 11), q = (int)(row & 2047);
  #pragma unroll
  for (int half = 0; half < 2; half++) {
    int col = threadIdx.x + half * 256;
    int h = col >> 6, hd = col & 63;
    int bh = b * 8 + h;
    float l = 0.f, v = 0.f;
    #pragma unroll
    for (int sp = 0; sp < 4; sp++) {
      l += lpart[(long)(sp * 32 + bh) * 2048 + q];
      v += bf2f(opart[((long)(sp * 32 + bh) * 2048 + q) * 64 + hd]);
    }
    ao[row * 512 + col] = bf16r(v / l);
  }
}

// ---------------- layernorm rows, fp32 in; OUTF 0 = bf16 out, 1 = f32 out ----
template <int OUTF>
__global__ __launch_bounds__(256) void ln_kernel(const float* __restrict__ in,
                                                 const float* __restrict__ gam,
                                                 const float* __restrict__ bet,
                                                 void* __restrict__ out) {
  const long row = blockIdx.x;
  const float* x = in + row * 512;
  float v0 = x[threadIdx.x], v1 = x[threadIdx.x + 256];
  float s = v0 + v1, ss = v0 * v0 + v1 * v1;
  #pragma unroll
  for (int off = 32; off > 0; off >>= 1) {
    s += __shfl_down(s, off, 64);
    ss += __shfl_down(ss, off, 64);
  }
  __shared__ float red[8];
  __shared__ float mv[2];
  int w = threadIdx.x >> 6, ln = threadIdx.x & 63;
  if (ln == 0) { red[w] = s; red[w + 4] = ss; }
  __syncthreads();
  if (threadIdx.x == 0) {
    float S = red[0] + red[1] + red[2] + red[3];
    float SS = red[4] + red[5] + red[6] + red[7];
    float mu = S * (1.f / 512.f);
    float var = SS * (1.f / 512.f) - mu * mu;
    mv[0] = mu;
    mv[1] = rsqrtf(var + 1e-5f);
  }
  __syncthreads();
  float mu = mv[0], rs = mv[1];
  float o0 = (v0 - mu) * rs * gam[threadIdx.x] + bet[threadIdx.x];
  float o1 = (v1 - mu) * rs * gam[threadIdx.x + 256] + bet[threadIdx.x + 256];
  if (OUTF == 0) {
    ((unsigned short*)out)[row * 512 + threadIdx.x] = bf16r(o0);
    ((unsigned short*)out)[row * 512 + threadIdx.x + 256] = bf16r(o1);
  } else {
    ((float*)out)[row * 512 + threadIdx.x] = o0;
    ((float*)out)[row * 512 + threadIdx.x + 256] = o1;
  }
}

// ---------------- pool: alpha = leaky_relu(h @ pw + pb) + mask*-1e16 ---------
__global__ __launch_bounds__(256) void alpha_kernel(const float* __restrict__ h,
                                                    const float* __restrict__ pw,
                                                    const float* __restrict__ pbias,
                                                    const float* __restrict__ mask,
                                                    float* __restrict__ alpha) {
  int w = threadIdx.x >> 6, ln = threadIdx.x & 63;
  long row = (long)blockIdx.x * 4 + w;
  float p[8];
  #pragma unroll
  for (int k = 0; k < 8; k++) p[k] = 0.f;
  #pragma unroll
  for (int it = 0; it < 8; it++) {
    int d = it * 64 + ln;
    float xv = h[row * 512 + d];
    const float* wr = pw + d * 8;
    #pragma unroll
    for (int k = 0; k < 8; k++) p[k] += xv * wr[k];
  }
  #pragma unroll
  for (int off = 32; off > 0; off >>= 1)
    #pragma unroll
    for (int k = 0; k < 8; k++) p[k] += __shfl_down(p[k], off, 64);
  if (ln == 0) {
    float mterm = mask[row] * (-1e16f);
    #pragma unroll
    for (int k = 0; k < 8; k++) {
      float a = p[k] + pbias[k];
      a = a < 0.f ? 0.01f * a : a;
      alpha[row * 8 + k] = a + mterm;
    }
  }
}

__global__ __launch_bounds__(256) void stats_kernel(const float* __restrict__ alpha,
                                                    float* __restrict__ stats) {
  int b = blockIdx.x >> 3, ph = blockIdx.x & 7;
  const float* a = alpha + (long)b * 2048 * 8 + ph;
  __shared__ float rr[4];
  __shared__ float mm[1];
  int w = threadIdx.x >> 6, ln = threadIdx.x & 63;
  float m = -1e38f;
  for (int s = threadIdx.x; s < 2048; s += 256) m = fmaxf(m, a[(long)s * 8]);
  #pragma unroll
  for (int off = 32; off > 0; off >>= 1) m = fmaxf(m, __shfl_down(m, off, 64));
  if (ln == 0) rr[w] = m;
  __syncthreads();
  if (threadIdx.x == 0) mm[0] = fmaxf(fmaxf(rr[0], rr[1]), fmaxf(rr[2], rr[3]));
  __syncthreads();
  float M = mm[0];
  float sum = 0.f;
  for (int s = threadIdx.x; s < 2048; s += 256) sum += __expf(a[(long)s * 8] - M);
  #pragma unroll
  for (int off = 32; off > 0; off >>= 1) sum += __shfl_down(sum, off, 64);
  __syncthreads();
  if (ln == 0) rr[w] = sum;
  __syncthreads();
  if (threadIdx.x == 0) {
    stats[blockIdx.x * 2] = M;
    stats[blockIdx.x * 2 + 1] = rr[0] + rr[1] + rr[2] + rr[3];
  }
}

// partial[sc + b*8][d] = sum over its 256-seq chunk of w(s) * h[s][d]
__global__ __launch_bounds__(256) void pool_kernel(const float* __restrict__ h,
                                                   const float* __restrict__ alpha,
                                                   const float* __restrict__ stats,
                                                   float* __restrict__ partial) {
  int b = blockIdx.x >> 3, sc = blockIdx.x & 7;
  int s0 = sc * 256;
  __shared__ float wb[256];
  {
    long s = s0 + threadIdx.x;
    const float* a = alpha + ((long)b * 2048 + s) * 8;
    float wsum = 0.f;
    #pragma unroll
    for (int ph = 0; ph < 8; ph++) {
      float M = stats[(b * 8 + ph) * 2], Sm = stats[(b * 8 + ph) * 2 + 1];
      wsum += __expf(a[ph] - M) / Sm;
    }
    wb[threadIdx.x] = wsum;
  }
  __syncthreads();
  float a0 = 0.f, a1 = 0.f;
  const float* hb = h + ((long)b * 2048 + s0) * 512;
  for (int i = 0; i < 256; i++) {
    float wv = wb[i];
    a0 += wv * hb[(long)i * 512 + threadIdx.x];
    a1 += wv * hb[(long)i * 512 + threadIdx.x + 256];
  }
  partial[(long)blockIdx.x * 512 + threadIdx.x] = a0;
  partial[(long)blockIdx.x * 512 + threadIdx.x + 256] = a1;
}

__global__ __launch_bounds__(256) void pool_final(const float* __restrict__ partial,
                                                  float* __restrict__ out) {
  int b = blockIdx.x;
  float a0 = 0.f, a1 = 0.f;
  #pragma unroll
  for (int sc = 0; sc < 8; sc++) {
    a0 += partial[(long)(b * 8 + sc) * 512 + threadIdx.x];
    a1 += partial[(long)(b * 8 + sc) * 512 + threadIdx.x + 256];
  }
  out[b * 512 + threadIdx.x] = a0;
  out[b * 512 + threadIdx.x + 256] = a1;
}

// -----------------------------------------------------------------------------
extern "C" void kernel_launch(void* const* d_in, const int* in_sizes, int n_in,
                              void* d_out, int out_size, void* d_ws, size_t ws_size,
                              hipStream_t stream) {
  (void)in_sizes; (void)n_in; (void)out_size;
  if (ws_size < 92274688UL) return;  // need ~88MB scratch

  const float* x    = (const float*)d_in[0];
  const float* mask = (const float*)d_in[1];
  const float* q1w = (const float*)d_in[2];  const float* q1b = (const float*)d_in[3];
  const float* k1w = (const float*)d_in[4];  const float* k1b = (const float*)d_in[5];
  const float* v1w = (const float*)d_in[6];  const float* v1b = (const float*)d_in[7];
  const float* o1w = (const float*)d_in[8];  const float* o1b = (const float*)d_in[9];
  const float* q2w = (const float*)d_in[10]; const float* q2b = (const float*)d_in[11];
  const float* k2w = (const float*)d_in[12]; const float* k2b = (const float*)d_in[13];
  const float* v2w = (const float*)d_in[14]; const float* v2b = (const float*)d_in[15];
  const float* o2w = (const float*)d_in[16]; const float* o2b = (const float*)d_in[17];
  const float* ln1g = (const float*)d_in[18]; const float* ln1b = (const float*)d_in[19];
  const float* fw1 = (const float*)d_in[20]; const float* fb1 = (const float*)d_in[21];
  const float* fw2 = (const float*)d_in[22]; const float* fb2 = (const float*)d_in[23];
  const float* ln2g = (const float*)d_in[24]; const float* ln2b = (const float*)d_in[25];
  const float* poolw = (const float*)d_in[26]; const float* poolb = (const float*)d_in[27];

  char* ws = (char*)d_ws;
  unsigned short* Wt  = (unsigned short*)(ws + 0);          // 10 x 512x512 bf16 (5MB)
  float* qb1          = (float*)(ws + 5242880);
  float* qb2          = (float*)(ws + 5249024);
  float* stats        = (float*)(ws + 5255168);
  float* alpha        = (float*)(ws + 5255424);             // 256KB
  float* partial      = (float*)(ws + 5517568);             // 64KB
  unsigned short* qkv = (unsigned short*)(ws + 8388608);    // [8192][1536] bf16 (24MB)
  unsigned short* vt  = (unsigned short*)(ws + 33554432);   // [32][64][2048] bf16 (8MB)
  unsigned short* ao  = (unsigned short*)(ws + 41943040);   // [8192][512] bf16 (8MB)
  float* t            = (float*)(ws + 50331648);            // [8192][512] f32 (16MB)
  unsigned short* xn  = (unsigned short*)(ws + 67108864);   // [8192][512] bf16 (8MB)
  unsigned short* h1  = (unsigned short*)(ws + 75497472);   // (8MB)
  unsigned short* f   = (unsigned short*)(ws + 83886080);   // (8MB)
  unsigned short* h2  = xn;                                 // xn dead by then
  // attention split-K partials: live ONLY during attn+combine; [t..f) = 32MiB
  // is dead there. opart = exactly 32MiB; lpart (1MB) in dead f region.
  unsigned short* opart = (unsigned short*)(ws + 50331648); // 32MiB [4][32][2048][64] bf16
  float* lpart          = (float*)(ws + 83886080);          // 1MB [4][32][2048] f32

  PrepArgs pa;
  pa.w[0] = q1w; pa.w[1] = k1w; pa.w[2] = v1w; pa.w[3] = o1w; pa.w[4] = fw1;
  pa.w[5] = fw2; pa.w[6] = q2w; pa.w[7] = k2w; pa.w[8] = v2w; pa.w[9] = o2w;
  pa.b1[0] = q1b; pa.b1[1] = k1b; pa.b1[2] = v1b;
  pa.b2[0] = q2b; pa.b2[1] = k2b; pa.b2[2] = v2b;

  prep_kernel<<<dim3(8, 8, 10), 256, 0, stream>>>(pa, Wt, qb1, qb2);
  l2norm_kernel<<<8192, 256, 0, stream>>>(x, xn);

  // layer 1 (QKV GEMM writes V directly transposed into vt)
  gemm_bt<3><<<dim3(64, 12), 256, 0, stream>>>(xn, Wt, qb1, qkv, 512, 1536, vt);
  attn_split_kernel<<<dim3(16, 32, 4), 256, 0, stream>>>(qkv, vt, mask, opart, lpart);
  attn_combine<<<8192, 256, 0, stream>>>(opart, lpart, ao);
  gemm_bt64<0><<<dim3(64, 8), 256, 0, stream>>>(ao, Wt + 3L * 512 * 512, o1b, t, 512, 512);
  ln_kernel<0><<<8192, 256, 0, stream>>>(t, ln1g, ln1b, h1);
  gemm_bt64<2><<<dim3(64, 8), 256, 0, stream>>>(h1, Wt + 4L * 512 * 512, fb1, f, 512, 512);
  gemm_bt64<1><<<dim3(64, 8), 256, 0, stream>>>(f, Wt + 5L * 512 * 512, fb2, h2, 512, 512);

  // layer 2
  gemm_bt<3><<<dim3(64, 12), 256, 0, stream>>>(h2, Wt + 6L * 512 * 512, qb2, qkv, 512, 1536, vt);
  attn_split_kernel<<<dim3(16, 32, 4), 256, 0, stream>>>(qkv, vt, mask, opart, lpart);
  attn_combine<<<8192, 256, 0, stream>>>(opart, lpart, ao);
  gemm_bt64<0><<<dim3(64, 8), 256, 0, stream>>>(ao, Wt + 9L * 512 * 512, o2b, t, 512, 512);
  ln_kernel<1><<<8192, 256, 0, stream>>>(t, ln2g, ln2b, t);  // in-place f32

  // pooling
  alpha_kernel<<<2048, 256, 0, stream>>>(t, poolw, poolb, mask, alpha);
  stats_kernel<<<32, 256, 0, stream>>>(alpha, stats);
  pool_kernel<<<32, 256, 0, stream>>>(t, alpha, stats, partial);
  pool_final<<<4, 256, 0, stream>>>(partial, (float*)d_out);
}

// Round 13
// 292.512 us; speedup vs baseline: 1.0491x; 1.0185x over previous
//
#include <hip/hip_runtime.h>
#include <hip/hip_bf16.h>
#include <stdint.h>

#define DEVI __device__ __forceinline__

typedef float f32x4 __attribute__((ext_vector_type(4)));
typedef float f32x16 __attribute__((ext_vector_type(16)));
typedef short bf16x8 __attribute__((ext_vector_type(8)));

typedef __attribute__((address_space(3))) unsigned int as3_u32;
typedef __attribute__((address_space(1))) unsigned int as1_u32;

DEVI void gload16(const void* g, void* l) {
  __builtin_amdgcn_global_load_lds((const as1_u32*)g, (as3_u32*)l, 16, 0, 0);
}

DEVI unsigned short bf16r(float f) {
  union { float f; unsigned int u; } v; v.f = f;
  unsigned int u = v.u;
  return (unsigned short)((u + 0x7FFFu + ((u >> 16) & 1u)) >> 16);
}

DEVI unsigned int pkbf16(float a, float b) {
  __hip_bfloat162 h = __float22bfloat162_rn(make_float2(a, b));
  return *(unsigned int*)&h;
}

// ---------------- weight prep: fp32 [K][N] -> bf16 [N][K], pack qkv biases ----
struct PrepArgs {
  const float* w[10];
  const float* b1[3];
  const float* b2[3];
};

__global__ __launch_bounds__(256) void prep_kernel(PrepArgs pa, unsigned short* wt,
                                                   float* qb1, float* qb2) {
  __shared__ float lt[64][65];
  const int slot = blockIdx.z;
  const int n0 = blockIdx.x * 64, k0 = blockIdx.y * 64;
  const float* W = pa.w[slot];
  for (int it = 0; it < 16; it++) {
    int idx = it * 256 + threadIdx.x;
    int kr = idx >> 6, nc = idx & 63;
    lt[kr][nc] = W[(long)(k0 + kr) * 512 + n0 + nc];
  }
  __syncthreads();
  unsigned short* dst = wt + (long)slot * 512 * 512;
  for (int it = 0; it < 16; it++) {
    int idx = it * 256 + threadIdx.x;
    int nr = idx >> 6, kc = idx & 63;
    dst[(long)(n0 + nr) * 512 + k0 + kc] = bf16r(lt[kc][nr]);
  }
  if (blockIdx.x == 0 && blockIdx.y == 0) {
    if (slot < 3) {
      for (int i = threadIdx.x; i < 512; i += 256) qb1[slot * 512 + i] = pa.b1[slot][i];
    } else if (slot >= 6 && slot < 9) {
      for (int i = threadIdx.x; i < 512; i += 256) qb2[(slot - 6) * 512 + i] = pa.b2[slot - 6][i];
    }
  }
}

// ---------------- l2 normalize rows of x, fp32 -> bf16 -----------------------
__global__ __launch_bounds__(256) void l2norm_kernel(const float* __restrict__ x,
                                                     unsigned short* __restrict__ xn) {
  const long row = blockIdx.x;
  const float* xr = x + row * 512;
  float v0 = xr[threadIdx.x], v1 = xr[threadIdx.x + 256];
  float ss = v0 * v0 + v1 * v1;
  #pragma unroll
  for (int off = 32; off > 0; off >>= 1) ss += __shfl_down(ss, off, 64);
  __shared__ float red[4];
  __shared__ float sc[1];
  int w = threadIdx.x >> 6, ln = threadIdx.x & 63;
  if (ln == 0) red[w] = ss;
  __syncthreads();
  if (threadIdx.x == 0) {
    float S = red[0] + red[1] + red[2] + red[3];
    sc[0] = 1.0f / fmaxf(sqrtf(S), 1e-12f);
  }
  __syncthreads();
  float s = sc[0];
  xn[row * 512 + threadIdx.x] = bf16r(v0 * s);
  xn[row * 512 + threadIdx.x + 256] = bf16r(v1 * s);
}

// ---------------- GEMM 128x128: C = A x Bt^T + bias --------------------------
// EPI: 0 = f32 out, 1 = bf16 out, 2 = bf16 out + relu,
//      3 = bf16 out; cols >=1024 are V -> written transposed into vtout
template <int EPI>
__global__ __launch_bounds__(256) void gemm_bt(const unsigned short* __restrict__ A,
                                               const unsigned short* __restrict__ Bt,
                                               const float* __restrict__ bias,
                                               void* __restrict__ Cv, int K, int N,
                                               unsigned short* __restrict__ vtout) {
  __shared__ unsigned short ldsA[128 * 64];
  __shared__ unsigned short ldsB[128 * 64];
  const int tid = threadIdx.x, w = tid >> 6, ln = tid & 63;
  const int bm = blockIdx.x, bn = blockIdx.y;
  const int wm = (w >> 1) * 64, wn = (w & 1) * 64;
  const f32x4 zf = {0.f, 0.f, 0.f, 0.f};
  f32x4 acc[4][4];
  #pragma unroll
  for (int i = 0; i < 4; i++)
    #pragma unroll
    for (int j = 0; j < 4; j++) acc[i][j] = zf;
  const int r8 = ln >> 3, s8 = ln & 7;
  for (int kt = 0; kt < K; kt += 64) {
    #pragma unroll
    for (int i = 0; i < 4; i++) {
      int row = w * 32 + i * 8 + r8;
      gload16(A + (long)(bm * 128 + row) * K + kt + s8 * 8, &ldsA[(w * 32 + i * 8) * 64]);
      gload16(Bt + (long)(bn * 128 + row) * K + kt + s8 * 8, &ldsB[(w * 32 + i * 8) * 64]);
    }
    __syncthreads();
    #pragma unroll
    for (int kk = 0; kk < 2; kk++) {
      bf16x8 af[4], bfr[4];
      #pragma unroll
      for (int mf = 0; mf < 4; mf++) {
        int row = wm + mf * 16 + (ln & 15);
        af[mf] = *(const bf16x8*)&ldsA[row * 64 + kk * 32 + (ln >> 4) * 8];
      }
      #pragma unroll
      for (int nf = 0; nf < 4; nf++) {
        int row = wn + nf * 16 + (ln & 15);
        bfr[nf] = *(const bf16x8*)&ldsB[row * 64 + kk * 32 + (ln >> 4) * 8];
      }
      #pragma unroll
      for (int mf = 0; mf < 4; mf++)
        #pragma unroll
        for (int nf = 0; nf < 4; nf++)
          acc[mf][nf] = __builtin_amdgcn_mfma_f32_16x16x32_bf16(af[mf], bfr[nf], acc[mf][nf], 0, 0, 0);
    }
    __syncthreads();
  }
  const int g = ln >> 4, c = ln & 15;
  #pragma unroll
  for (int mf = 0; mf < 4; mf++) {
    #pragma unroll
    for (int nf = 0; nf < 4; nf++) {
      int col = bn * 128 + wn + nf * 16 + c;
      float bv = bias[col];
      if (EPI == 3 && col >= 1024) {
        long row0 = bm * 128 + wm + mf * 16 + g * 4;
        int b = (int)(row0 >> 11), s = (int)(row0 & 2047);
        int vc = col - 1024, h = vc >> 6, hd = vc & 63;
        ushort4 o;
        o.x = bf16r(acc[mf][nf][0] + bv);
        o.y = bf16r(acc[mf][nf][1] + bv);
        o.z = bf16r(acc[mf][nf][2] + bv);
        o.w = bf16r(acc[mf][nf][3] + bv);
        *(ushort4*)(vtout + ((long)((b * 8 + h) * 64 + hd)) * 2048 + s) = o;
      } else {
        #pragma unroll
        for (int j = 0; j < 4; j++) {
          long row = bm * 128 + wm + mf * 16 + g * 4 + j;
          float v = acc[mf][nf][j] + bv;
          if (EPI == 2) v = v > 0.f ? v : 0.f;
          if (EPI == 0)
            ((float*)Cv)[row * N + col] = v;
          else
            ((unsigned short*)Cv)[row * N + col] = bf16r(v);
        }
      }
    }
  }
}

// ---------------- GEMM 128x64 tile (for N=512 chains: 512 blocks, 2/CU) ------
template <int EPI>
__global__ __launch_bounds__(256) void gemm_bt64(const unsigned short* __restrict__ A,
                                                 const unsigned short* __restrict__ Bt,
                                                 const float* __restrict__ bias,
                                                 void* __restrict__ Cv, int K, int N) {
  __shared__ unsigned short ldsA[128 * 64];
  __shared__ unsigned short ldsB[64 * 64];
  const int tid = threadIdx.x, w = tid >> 6, ln = tid & 63;
  const int bm = blockIdx.x, bn = blockIdx.y;
  const int wm = (w >> 1) * 64, wn = (w & 1) * 32;
  const f32x4 zf = {0.f, 0.f, 0.f, 0.f};
  f32x4 acc[4][2];
  #pragma unroll
  for (int i = 0; i < 4; i++)
    #pragma unroll
    for (int j = 0; j < 2; j++) acc[i][j] = zf;
  const int r8 = ln >> 3, s8 = ln & 7;
  for (int kt = 0; kt < K; kt += 64) {
    #pragma unroll
    for (int i = 0; i < 6; i++) {
      int jj = w * 6 + i;
      if (jj < 16) {
        gload16(A + (long)(bm * 128 + jj * 8 + r8) * K + kt + s8 * 8, &ldsA[jj * 512]);
      } else {
        int jb = jj - 16;
        gload16(Bt + (long)(bn * 64 + jb * 8 + r8) * K + kt + s8 * 8, &ldsB[jb * 512]);
      }
    }
    __syncthreads();
    #pragma unroll
    for (int kk = 0; kk < 2; kk++) {
      bf16x8 af[4], bfr[2];
      #pragma unroll
      for (int mf = 0; mf < 4; mf++)
        af[mf] = *(const bf16x8*)&ldsA[(wm + mf * 16 + (ln & 15)) * 64 + kk * 32 + (ln >> 4) * 8];
      #pragma unroll
      for (int nf = 0; nf < 2; nf++)
        bfr[nf] = *(const bf16x8*)&ldsB[(wn + nf * 16 + (ln & 15)) * 64 + kk * 32 + (ln >> 4) * 8];
      #pragma unroll
      for (int mf = 0; mf < 4; mf++)
        #pragma unroll
        for (int nf = 0; nf < 2; nf++)
          acc[mf][nf] = __builtin_amdgcn_mfma_f32_16x16x32_bf16(af[mf], bfr[nf], acc[mf][nf], 0, 0, 0);
    }
    __syncthreads();
  }
  const int g = ln >> 4, c = ln & 15;
  #pragma unroll
  for (int mf = 0; mf < 4; mf++) {
    #pragma unroll
    for (int nf = 0; nf < 2; nf++) {
      int col = bn * 64 + wn + nf * 16 + c;
      float bv = bias[col];
      #pragma unroll
      for (int j = 0; j < 4; j++) {
        long row = bm * 128 + wm + mf * 16 + g * 4 + j;
        float v = acc[mf][nf][j] + bv;
        if (EPI == 2) v = v > 0.f ? v : 0.f;
        if (EPI == 0)
          ((float*)Cv)[row * N + col] = v;
        else
          ((unsigned short*)Cv)[row * N + col] = bf16r(v);
      }
    }
  }
}

// ---------------- fused attention, FULL-K, 32x32 MFMA, in-register P ---------
// No split-K: each block owns 2048 keys for its 128 queries, normalizes
// in-register and writes ao directly (combine kernel eliminated).
__global__ __launch_bounds__(256, 4) void attn_kernel(
    const unsigned short* __restrict__ qkv,
    const unsigned short* __restrict__ vt,
    const float* __restrict__ mask,
    unsigned short* __restrict__ ao) {
  const int tid = threadIdx.x, w = tid >> 6, ln = tid & 63;
  const int lo = ln & 31, hi = ln >> 5;
  // XCD-aware bijective swizzle (512 = 8 x 64)
  const int bid = blockIdx.x + 16 * blockIdx.y;
  const int swz = (bid & 7) * 64 + (bid >> 3);
  const int qb = swz & 15, bh = swz >> 4;
  const int b = bh >> 3, h = bh & 7;
  const int q0 = qb * 128 + w * 32;
  const unsigned short* qp = qkv + (long)(b * 2048) * 1536 + h * 64;
  const unsigned short* kp = qp + 512;
  const unsigned short* vtp = vt + (long)bh * 64 * 2048;
  const float* mp = mask + b * 2048;

  // K region: [0,2048) = 32 rows x 64; V region: [2048,4096) = 64 rows x 32
  __shared__ unsigned short sbuf[2][4096];   // 8KB per buffer
  __shared__ float mbuf[2048];
  __shared__ int mflag;

  // ---- mask -> LDS, block-uniform anymask flag
  {
    float acc = 0.f;
    #pragma unroll
    for (int i = 0; i < 8; i++) {
      float mv = mp[i * 256 + tid];
      mbuf[i * 256 + tid] = mv;
      acc += fabsf(mv);
    }
    if (tid == 0) mflag = 0;
    __syncthreads();
    if (acc != 0.f) mflag = 1;
    __syncthreads();
  }
  const bool anymask = (mflag != 0);

  // ---- staging: per-wave 2 chunks; pointers strength-reduced
  const int jj0 = w * 2;
  const char *src0, *src1;
  long step;
  if (w < 2) {  // K chunks jj0, jj0+1 (rows 8 apart)
    int r0 = jj0 * 8 + (ln >> 3), r1 = r0 + 8, s = ln & 7;
    src0 = (const char*)kp + 2L * ((long)r0 * 1536 + ((s ^ (r0 & 7)) * 8));
    src1 = (const char*)kp + 2L * ((long)r1 * 1536 + ((s ^ (r1 & 7)) * 8));
    step = 32L * 1536 * 2;
  } else {      // V chunks j0, j0+1 (hd rows 16 apart)
    int j0 = (w - 2) * 2;
    int r0 = j0 * 16 + (ln >> 2), r1 = r0 + 16, s = ln & 3;
    src0 = (const char*)vtp + 2L * ((long)r0 * 2048 + ((s ^ ((r0 >> 1) & 3)) * 8));
    src1 = (const char*)vtp + 2L * ((long)r1 * 2048 + ((s ^ ((r1 >> 1) & 3)) * 8));
    step = 64;
  }
  unsigned short* const d0a = &sbuf[0][jj0 * 512];
  unsigned short* const d0b = d0a + 512;
  unsigned short* const d1a = &sbuf[1][jj0 * 512];
  unsigned short* const d1b = d1a + 512;

  // ---- loop-invariant LDS read offsets (elements)
  int koffe[4];
  #pragma unroll
  for (int t = 0; t < 4; t++)
    koffe[t] = lo * 64 + (((t * 2 + hi) ^ (lo & 7)) * 8);
  int voffe[4];
  #pragma unroll
  for (int stt = 0; stt < 2; stt++)
    #pragma unroll
    for (int tau = 0; tau < 2; tau++) {
      int vr = tau * 32 + lo;
      voffe[stt * 2 + tau] = 2048 + vr * 32 + ((((stt * 2 + hi) ^ ((vr >> 1) & 3))) * 8);
    }

  // ---- Q fragments (B-operand, hoisted)
  bf16x8 qf[4];
  #pragma unroll
  for (int t = 0; t < 4; t++)
    qf[t] = *(const bf16x8*)(qp + (long)(q0 + lo) * 1536 + t * 16 + hi * 8);

  f32x16 oacc[2];
  #pragma unroll
  for (int t = 0; t < 2; t++)
    #pragma unroll
    for (int r = 0; r < 16; r++) oacc[t][r] = 0.f;
  float lsum = 0.f;
  const f32x16 zf16 = oacc[0];
  const float SC = 0.18033688011112042f;  // 0.125 * log2(e)

  // prologue stage into buf0
  gload16(src0, d0a);
  gload16(src1, d0b);
  src0 += step; src1 += step;

#define ATTN_BODY(CURB, DA, DB, ITOFF, STAGE_NEXT)                              \
  {                                                                             \
    if (STAGE_NEXT) {                                                           \
      gload16(src0, DA);                                                        \
      gload16(src1, DB);                                                        \
      src0 += step; src1 += step;                                               \
      asm volatile("s_waitcnt vmcnt(2)" ::: "memory");                          \
    } else {                                                                    \
      asm volatile("s_waitcnt vmcnt(0)" ::: "memory");                          \
    }                                                                           \
    __builtin_amdgcn_s_barrier();                                               \
    __builtin_amdgcn_sched_barrier(0);                                          \
    f32x16 sacc = zf16;                                                         \
    _Pragma("unroll")                                                           \
    for (int t = 0; t < 4; t++) {                                               \
      bf16x8 kf = *(const bf16x8*)&sbuf[CURB][koffe[t]];                        \
      sacc = __builtin_amdgcn_mfma_f32_32x32x16_bf16(kf, qf[t], sacc, 0, 0, 0); \
    }                                                                           \
    float e[16];                                                                \
    _Pragma("unroll")                                                           \
    for (int r = 0; r < 16; r++) e[r] = sacc[r] * SC;                           \
    if (anymask) {                                                              \
      float mval = mbuf[(ITOFF) + lo];                                          \
      _Pragma("unroll")                                                         \
      for (int r = 0; r < 16; r++)                                              \
        e[r] -= 1.4426950408889634e30f *                                        \
                __shfl(mval, (r & 3) + 8 * (r >> 2) + 4 * hi, 64);              \
    }                                                                           \
    _Pragma("unroll")                                                           \
    for (int r = 0; r < 16; r++) e[r] = __builtin_amdgcn_exp2f(e[r]);           \
    _Pragma("unroll")                                                           \
    for (int r = 0; r < 16; r++) lsum += e[r];                                  \
    unsigned int cv[8];                                                         \
    _Pragma("unroll")                                                           \
    for (int i = 0; i < 8; i++) cv[i] = pkbf16(e[2 * i], e[2 * i + 1]);         \
    _Pragma("unroll")                                                           \
    for (int stt = 0; stt < 2; stt++) {                                         \
      unsigned int pf[4];                                                       \
      {                                                                         \
        auto r0_ = __builtin_amdgcn_permlane32_swap(cv[stt * 4 + 0],            \
                                                    cv[stt * 4 + 2], false, false); \
        auto r1_ = __builtin_amdgcn_permlane32_swap(cv[stt * 4 + 1],            \
                                                    cv[stt * 4 + 3], false, false); \
        pf[0] = r0_[0]; pf[1] = r1_[0]; pf[2] = r0_[1]; pf[3] = r1_[1];         \
      }                                                                         \
      bf16x8 pfr = *(const bf16x8*)pf;                                          \
      _Pragma("unroll")                                                         \
      for (int tau = 0; tau < 2; tau++) {                                       \
        bf16x8 vf = *(const bf16x8*)&sbuf[CURB][voffe[stt * 2 + tau]];          \
        oacc[tau] = __builtin_amdgcn_mfma_f32_32x32x16_bf16(vf, pfr, oacc[tau], 0, 0, 0); \
      }                                                                         \
    }                                                                           \
    __builtin_amdgcn_sched_barrier(0);                                          \
    __builtin_amdgcn_s_barrier();                                               \
  }

  for (int it2 = 0; it2 < 32; it2++) {
    ATTN_BODY(0, d1a, d1b, it2 * 64, 1)
    ATTN_BODY(1, d0a, d0b, it2 * 64 + 32, (it2 < 31))
  }
#undef ATTN_BODY

  lsum += __shfl_xor(lsum, 32, 64);
  const float inv = 1.f / lsum;
  unsigned short* ob = ao + ((long)(b * 2048) + q0 + lo) * 512 + h * 64;
  #pragma unroll
  for (int tau = 0; tau < 2; tau++) {
    #pragma unroll
    for (int j = 0; j < 4; j++) {
      ushort4 o;
      o.x = bf16r(oacc[tau][4 * j + 0] * inv);
      o.y = bf16r(oacc[tau][4 * j + 1] * inv);
      o.z = bf16r(oacc[tau][4 * j + 2] * inv);
      o.w = bf16r(oacc[tau][4 * j + 3] * inv);
      *(ushort4*)(ob + tau * 32 + j * 8 + hi * 4) = o;
    }
  }
}

// ---------------- layernorm rows, fp32 in -> bf16 out ------------------------
__global__ __launch_bounds__(256) void ln_kernel(const float* __restrict__ in,
                                                 const float* __restrict__ gam,
                                                 const float* __restrict__ bet,
                                                 unsigned short* __restrict__ out) {
  const long row = blockIdx.x;
  const float* x = in + row * 512;
  float v0 = x[threadIdx.x], v1 = x[threadIdx.x + 256];
  float s = v0 + v1, ss = v0 * v0 + v1 * v1;
  #pragma unroll
  for (int off = 32; off > 0; off >>= 1) {
    s += __shfl_down(s, off, 64);
    ss += __shfl_down(ss, off, 64);
  }
  __shared__ float red[8];
  __shared__ float mv[2];
  int w = threadIdx.x >> 6, ln = threadIdx.x & 63;
  if (ln == 0) { red[w] = s; red[w + 4] = ss; }
  __syncthreads();
  if (threadIdx.x == 0) {
    float S = red[0] + red[1] + red[2] + red[3];
    float SS = red[4] + red[5] + red[6] + red[7];
    float mu = S * (1.f / 512.f);
    float var = SS * (1.f / 512.f) - mu * mu;
    mv[0] = mu;
    mv[1] = rsqrtf(var + 1e-5f);
  }
  __syncthreads();
  float mu = mv[0], rs = mv[1];
  float o0 = (v0 - mu) * rs * gam[threadIdx.x] + bet[threadIdx.x];
  float o1 = (v1 - mu) * rs * gam[threadIdx.x + 256] + bet[threadIdx.x + 256];
  out[row * 512 + threadIdx.x] = bf16r(o0);
  out[row * 512 + threadIdx.x + 256] = bf16r(o1);
}

// ---------------- LN2 + fused alpha: ln -> t (f32); alpha = leaky(t@pw+pb) ---
__global__ __launch_bounds__(256) void ln2_alpha_kernel(const float* __restrict__ in,
                                                        const float* __restrict__ gam,
                                                        const float* __restrict__ bet,
                                                        const float* __restrict__ pw,
                                                        const float* __restrict__ pbias,
                                                        const float* __restrict__ mask,
                                                        float* __restrict__ out,
                                                        float* __restrict__ alpha) {
  const long row = blockIdx.x;
  const float* x = in + row * 512;
  float v0 = x[threadIdx.x], v1 = x[threadIdx.x + 256];
  float s = v0 + v1, ss = v0 * v0 + v1 * v1;
  #pragma unroll
  for (int off = 32; off > 0; off >>= 1) {
    s += __shfl_down(s, off, 64);
    ss += __shfl_down(ss, off, 64);
  }
  __shared__ float red[8];
  __shared__ float mv[2];
  __shared__ float pr[4][8];
  int w = threadIdx.x >> 6, ln = threadIdx.x & 63;
  if (ln == 0) { red[w] = s; red[w + 4] = ss; }
  __syncthreads();
  if (threadIdx.x == 0) {
    float S = red[0] + red[1] + red[2] + red[3];
    float SS = red[4] + red[5] + red[6] + red[7];
    float mu = S * (1.f / 512.f);
    float var = SS * (1.f / 512.f) - mu * mu;
    mv[0] = mu;
    mv[1] = rsqrtf(var + 1e-5f);
  }
  __syncthreads();
  float mu = mv[0], rs = mv[1];
  float o0 = (v0 - mu) * rs * gam[threadIdx.x] + bet[threadIdx.x];
  float o1 = (v1 - mu) * rs * gam[threadIdx.x + 256] + bet[threadIdx.x + 256];
  out[row * 512 + threadIdx.x] = o0;
  out[row * 512 + threadIdx.x + 256] = o1;
  // fused alpha: p[k] = sum_d t[row][d] * pw[d][k]
  float p[8];
  const float* w0 = pw + threadIdx.x * 8;
  const float* w1 = pw + (threadIdx.x + 256) * 8;
  #pragma unroll
  for (int k = 0; k < 8; k++) p[k] = o0 * w0[k] + o1 * w1[k];
  #pragma unroll
  for (int off = 32; off > 0; off >>= 1)
    #pragma unroll
    for (int k = 0; k < 8; k++) p[k] += __shfl_down(p[k], off, 64);
  if (ln == 0)
    #pragma unroll
    for (int k = 0; k < 8; k++) pr[w][k] = p[k];
  __syncthreads();
  if (threadIdx.x < 8) {
    float a = pr[0][threadIdx.x] + pr[1][threadIdx.x] + pr[2][threadIdx.x] + pr[3][threadIdx.x]
              + pbias[threadIdx.x];
    a = a < 0.f ? 0.01f * a : a;
    alpha[row * 8 + threadIdx.x] = a + mask[row] * (-1e16f);
  }
}

__global__ __launch_bounds__(256) void stats_kernel(const float* __restrict__ alpha,
                                                    float* __restrict__ stats) {
  int b = blockIdx.x >> 3, ph = blockIdx.x & 7;
  const float* a = alpha + (long)b * 2048 * 8 + ph;
  __shared__ float rr[4];
  __shared__ float mm[1];
  int w = threadIdx.x >> 6, ln = threadIdx.x & 63;
  float m = -1e38f;
  for (int s = threadIdx.x; s < 2048; s += 256) m = fmaxf(m, a[(long)s * 8]);
  #pragma unroll
  for (int off = 32; off > 0; off >>= 1) m = fmaxf(m, __shfl_down(m, off, 64));
  if (ln == 0) rr[w] = m;
  __syncthreads();
  if (threadIdx.x == 0) mm[0] = fmaxf(fmaxf(rr[0], rr[1]), fmaxf(rr[2], rr[3]));
  __syncthreads();
  float M = mm[0];
  float sum = 0.f;
  for (int s = threadIdx.x; s < 2048; s += 256) sum += __expf(a[(long)s * 8] - M);
  #pragma unroll
  for (int off = 32; off > 0; off >>= 1) sum += __shfl_down(sum, off, 64);
  __syncthreads();
  if (ln == 0) rr[w] = sum;
  __syncthreads();
  if (threadIdx.x == 0) {
    stats[blockIdx.x * 2] = M;
    stats[blockIdx.x * 2 + 1] = rr[0] + rr[1] + rr[2] + rr[3];
  }
}

// partial[sc + b*8][d] = sum over its 256-seq chunk of w(s) * h[s][d]
__global__ __launch_bounds__(256) void pool_kernel(const float* __restrict__ h,
                                                   const float* __restrict__ alpha,
                                                   const float* __restrict__ stats,
                                                   float* __restrict__ partial) {
  int b = blockIdx.x >> 3, sc = blockIdx.x & 7;
  int s0 = sc * 256;
  __shared__ float wb[256];
  {
    long s = s0 + threadIdx.x;
    const float* a = alpha + ((long)b * 2048 + s) * 8;
    float wsum = 0.f;
    #pragma unroll
    for (int ph = 0; ph < 8; ph++) {
      float M = stats[(b * 8 + ph) * 2], Sm = stats[(b * 8 + ph) * 2 + 1];
      wsum += __expf(a[ph] - M) / Sm;
    }
    wb[threadIdx.x] = wsum;
  }
  __syncthreads();
  float a0 = 0.f, a1 = 0.f;
  const float* hb = h + ((long)b * 2048 + s0) * 512;
  for (int i = 0; i < 256; i++) {
    float wv = wb[i];
    a0 += wv * hb[(long)i * 512 + threadIdx.x];
    a1 += wv * hb[(long)i * 512 + threadIdx.x + 256];
  }
  partial[(long)blockIdx.x * 512 + threadIdx.x] = a0;
  partial[(long)blockIdx.x * 512 + threadIdx.x + 256] = a1;
}

__global__ __launch_bounds__(256) void pool_final(const float* __restrict__ partial,
                                                  float* __restrict__ out) {
  int b = blockIdx.x;
  float a0 = 0.f, a1 = 0.f;
  #pragma unroll
  for (int sc = 0; sc < 8; sc++) {
    a0 += partial[(long)(b * 8 + sc) * 512 + threadIdx.x];
    a1 += partial[(long)(b * 8 + sc) * 512 + threadIdx.x + 256];
  }
  out[b * 512 + threadIdx.x] = a0;
  out[b * 512 + threadIdx.x + 256] = a1;
}

// -----------------------------------------------------------------------------
extern "C" void kernel_launch(void* const* d_in, const int* in_sizes, int n_in,
                              void* d_out, int out_size, void* d_ws, size_t ws_size,
                              hipStream_t stream) {
  (void)in_sizes; (void)n_in; (void)out_size;
  if (ws_size < 92274688UL) return;  // need ~88MB scratch

  const float* x    = (const float*)d_in[0];
  const float* mask = (const float*)d_in[1];
  const float* q1w = (const float*)d_in[2];  const float* q1b = (const float*)d_in[3];
  const float* k1w = (const float*)d_in[4];  const float* k1b = (const float*)d_in[5];
  const float* v1w = (const float*)d_in[6];  const float* v1b = (const float*)d_in[7];
  const float* o1w = (const float*)d_in[8];  const float* o1b = (const float*)d_in[9];
  const float* q2w = (const float*)d_in[10]; const float* q2b = (const float*)d_in[11];
  const float* k2w = (const float*)d_in[12]; const float* k2b = (const float*)d_in[13];
  const float* v2w = (const float*)d_in[14]; const float* v2b = (const float*)d_in[15];
  const float* o2w = (const float*)d_in[16]; const float* o2b = (const float*)d_in[17];
  const float* ln1g = (const float*)d_in[18]; const float* ln1b = (const float*)d_in[19];
  const float* fw1 = (const float*)d_in[20]; const float* fb1 = (const float*)d_in[21];
  const float* fw2 = (const float*)d_in[22]; const float* fb2 = (const float*)d_in[23];
  const float* ln2g = (const float*)d_in[24]; const float* ln2b = (const float*)d_in[25];
  const float* poolw = (const float*)d_in[26]; const float* poolb = (const float*)d_in[27];

  char* ws = (char*)d_ws;
  unsigned short* Wt  = (unsigned short*)(ws + 0);          // 10 x 512x512 bf16 (5MB)
  float* qb1          = (float*)(ws + 5242880);
  float* qb2          = (float*)(ws + 5249024);
  float* stats        = (float*)(ws + 5255168);
  float* alpha        = (float*)(ws + 5255424);             // 256KB
  float* partial      = (float*)(ws + 5517568);             // 64KB
  unsigned short* qkv = (unsigned short*)(ws + 8388608);    // [8192][1536] bf16 (24MB)
  unsigned short* vt  = (unsigned short*)(ws + 33554432);   // [32][64][2048] bf16 (8MB)
  unsigned short* ao  = (unsigned short*)(ws + 41943040);   // [8192][512] bf16 (8MB)
  float* t            = (float*)(ws + 50331648);            // [8192][512] f32 (16MB)
  unsigned short* xn  = (unsigned short*)(ws + 67108864);   // [8192][512] bf16 (8MB)
  unsigned short* h1  = (unsigned short*)(ws + 75497472);   // (8MB)
  unsigned short* f   = (unsigned short*)(ws + 83886080);   // (8MB)
  unsigned short* h2  = xn;                                 // xn dead by then

  PrepArgs pa;
  pa.w[0] = q1w; pa.w[1] = k1w; pa.w[2] = v1w; pa.w[3] = o1w; pa.w[4] = fw1;
  pa.w[5] = fw2; pa.w[6] = q2w; pa.w[7] = k2w; pa.w[8] = v2w; pa.w[9] = o2w;
  pa.b1[0] = q1b; pa.b1[1] = k1b; pa.b1[2] = v1b;
  pa.b2[0] = q2b; pa.b2[1] = k2b; pa.b2[2] = v2b;

  prep_kernel<<<dim3(8, 8, 10), 256, 0, stream>>>(pa, Wt, qb1, qb2);
  l2norm_kernel<<<8192, 256, 0, stream>>>(x, xn);

  // layer 1 (QKV GEMM writes V directly transposed into vt)
  gemm_bt<3><<<dim3(64, 12), 256, 0, stream>>>(xn, Wt, qb1, qkv, 512, 1536, vt);
  attn_kernel<<<dim3(16, 32), 256, 0, stream>>>(qkv, vt, mask, ao);
  gemm_bt64<0><<<dim3(64, 8), 256, 0, stream>>>(ao, Wt + 3L * 512 * 512, o1b, t, 512, 512);
  ln_kernel<<<8192, 256, 0, stream>>>(t, ln1g, ln1b, h1);
  gemm_bt64<2><<<dim3(64, 8), 256, 0, stream>>>(h1, Wt + 4L * 512 * 512, fb1, f, 512, 512);
  gemm_bt64<1><<<dim3(64, 8), 256, 0, stream>>>(f, Wt + 5L * 512 * 512, fb2, h2, 512, 512);

  // layer 2
  gemm_bt<3><<<dim3(64, 12), 256, 0, stream>>>(h2, Wt + 6L * 512 * 512, qb2, qkv, 512, 1536, vt);
  attn_kernel<<<dim3(16, 32), 256, 0, stream>>>(qkv, vt, mask, ao);
  gemm_bt64<0><<<dim3(64, 8), 256, 0, stream>>>(ao, Wt + 9L * 512 * 512, o2b, t, 512, 512);
  ln2_alpha_kernel<<<8192, 256, 0, stream>>>(t, ln2g, ln2b, poolw, poolb, mask, t, alpha);

  // pooling
  stats_kernel<<<32, 256, 0, stream>>>(alpha, stats);
  pool_kernel<<<32, 256, 0, stream>>>(t, alpha, stats, partial);
  pool_final<<<4, 256, 0, stream>>>(partial, (float*)d_out);
}